// Round 1
// baseline (522.252 us; speedup 1.0000x reference)
//
#include <hip/hip_runtime.h>
#include <hip/hip_bf16.h>
#include <math.h>

typedef unsigned short u16;
typedef __attribute__((ext_vector_type(8))) __bf16 bf16x8;
typedef __attribute__((ext_vector_type(4))) float f32x4;

#define DIM   1024
#define LSEQ  2048
#define BTOK  4096
#define NH    16
#define HD    64
#define FFN   4096
#define SCALE 0.125f

__device__ __forceinline__ u16 f2bf(float f) {
  unsigned u = __builtin_bit_cast(unsigned, f);
  u += 0x7FFFu + ((u >> 16) & 1u);
  return (u16)(u >> 16);
}
__device__ __forceinline__ unsigned pk2(float a, float b) {
  return (unsigned)f2bf(a) | ((unsigned)f2bf(b) << 16);
}
__device__ __forceinline__ f32x4 mfma16(bf16x8 a, bf16x8 b, f32x4 c) {
  return __builtin_amdgcn_mfma_f32_16x16x32_bf16(a, b, c, 0, 0, 0);
}

// ---------------- LayerNorm (fp32 in -> bf16 out) ----------------
__global__ __launch_bounds__(256) void ln_kernel(const float* __restrict__ x,
                                                 const float* __restrict__ g,
                                                 const float* __restrict__ bta,
                                                 u16* __restrict__ out) {
  int row = blockIdx.x, t = threadIdx.x;
  const float* xr = x + (size_t)row * DIM;
  float4 xv = *(const float4*)(xr + t * 4);
  float s  = xv.x + xv.y + xv.z + xv.w;
  float ss = xv.x * xv.x + xv.y * xv.y + xv.z * xv.z + xv.w * xv.w;
#pragma unroll
  for (int m = 32; m >= 1; m >>= 1) {
    s  += __shfl_xor(s, m);
    ss += __shfl_xor(ss, m);
  }
  __shared__ float red[8];
  if ((t & 63) == 0) { red[(t >> 6) * 2] = s; red[(t >> 6) * 2 + 1] = ss; }
  __syncthreads();
  s  = red[0] + red[2] + red[4] + red[6];
  ss = red[1] + red[3] + red[5] + red[7];
  float mu  = s * (1.0f / DIM);
  float var = ss * (1.0f / DIM) - mu * mu;
  float rs  = rsqrtf(var + 1e-5f);
  float4 gv = *(const float4*)(g + t * 4);
  float4 bv = *(const float4*)(bta + t * 4);
  uint2 o;
  o.x = pk2((xv.x - mu) * rs * gv.x + bv.x, (xv.y - mu) * rs * gv.y + bv.y);
  o.y = pk2((xv.z - mu) * rs * gv.z + bv.z, (xv.w - mu) * rs * gv.w + bv.w);
  *(uint2*)(out + (size_t)row * DIM + t * 4) = o;
}

// ---------------- V transpose: v[b,l,h,c] -> vt[b,h,c,l] ----------------
__global__ __launch_bounds__(256) void transpose_v(const u16* __restrict__ v,
                                                   u16* __restrict__ vt) {
  __shared__ u16 tls[64][80];
  int jb = blockIdx.x, bh = blockIdx.y, b = bh >> 4, h = bh & 15;
  int t = threadIdx.x;
  int r = t >> 2, seg = t & 3;
  const u16* src = v + (size_t)(b * LSEQ + jb * 64 + r) * DIM + h * HD + seg * 16;
  *(uint4*)&tls[r][seg * 16]     = *(const uint4*)src;
  *(uint4*)&tls[r][seg * 16 + 8] = *(const uint4*)(src + 8);
  __syncthreads();
  int c = t >> 2, jseg = t & 3;
  u16 tmp[16] __attribute__((aligned(16)));
#pragma unroll
  for (int i = 0; i < 16; i++) tmp[i] = tls[jseg * 16 + i][c];
  u16* dst = vt + ((size_t)bh * HD + c) * LSEQ + jb * 64 + jseg * 16;
  *(uint4*)dst       = *(const uint4*)tmp;
  *(uint4*)(dst + 8) = *(const uint4*)(tmp + 8);
}

// ---------------- GEMM: C[M,N] = A[M,K](bf16) @ W[N,K](fp32)^T + bias ----------------
// EPI 0: out bf16 = acc+bias; 1: outF fp32 = acc+bias+resid; 2: out bf16 = gelu(acc+bias)
struct WSel { const float* W; const float* bias; u16* out; };

template <int BM, int EPI>
__global__ __launch_bounds__(256) void gemm_kernel(const u16* __restrict__ A,
                                                   WSel s0, WSel s1, WSel s2,
                                                   const float* __restrict__ resid,
                                                   float* __restrict__ outF,
                                                   int N, int K, int nbPerW) {
  constexpr int WM = BM / 32;  // 16-row fragments per wave
  __shared__ u16 lsa[BM * 40];
  __shared__ u16 lsb[128 * 40];
  int t = threadIdx.x;
  int w = t >> 6, l = t & 63, l15 = l & 15, lg = l >> 4;
  int wr = w >> 1, wc = w & 1;
  int sel = blockIdx.x / nbPerW;
  int nb  = blockIdx.x % nbPerW;
  WSel S = (sel == 0) ? s0 : ((sel == 1) ? s1 : s2);
  int n0 = nb * 128;
  int m0 = blockIdx.y * BM;

  f32x4 acc[WM][4];
#pragma unroll
  for (int m = 0; m < WM; m++)
#pragma unroll
    for (int n = 0; n < 4; n++) acc[m][n] = (f32x4){0.f, 0.f, 0.f, 0.f};

  int arow = (BM == 128) ? (t >> 1) : (t >> 2);
  int aseg = (BM == 128) ? (t & 1) : (t & 3);
  int brow = t >> 1, bseg = t & 1;
  const u16* Ag   = A + (size_t)(m0 + arow) * K;
  const float* Wg = S.W + (size_t)(n0 + brow) * K;

  for (int k0 = 0; k0 < K; k0 += 32) {
    __syncthreads();
    if (BM == 128) {
      uint4 va0 = *(const uint4*)(Ag + k0 + aseg * 16);
      uint4 va1 = *(const uint4*)(Ag + k0 + aseg * 16 + 8);
      *(uint4*)&lsa[arow * 40 + aseg * 16]     = va0;
      *(uint4*)&lsa[arow * 40 + aseg * 16 + 8] = va1;
    } else {
      uint4 va0 = *(const uint4*)(Ag + k0 + aseg * 8);
      *(uint4*)&lsa[arow * 40 + aseg * 8] = va0;
    }
    const float* wp = Wg + k0 + bseg * 16;
    float4 f0 = *(const float4*)(wp);
    float4 f1 = *(const float4*)(wp + 4);
    float4 f2 = *(const float4*)(wp + 8);
    float4 f3 = *(const float4*)(wp + 12);
    uint4 pa, pb;
    pa.x = pk2(f0.x, f0.y); pa.y = pk2(f0.z, f0.w);
    pa.z = pk2(f1.x, f1.y); pa.w = pk2(f1.z, f1.w);
    pb.x = pk2(f2.x, f2.y); pb.y = pk2(f2.z, f2.w);
    pb.z = pk2(f3.x, f3.y); pb.w = pk2(f3.z, f3.w);
    *(uint4*)&lsb[brow * 40 + bseg * 16]     = pa;
    *(uint4*)&lsb[brow * 40 + bseg * 16 + 8] = pb;
    __syncthreads();

    bf16x8 af[WM], bf[4];
#pragma unroll
    for (int m = 0; m < WM; m++)
      af[m] = *(const bf16x8*)&lsa[(wr * (BM / 2) + m * 16 + l15) * 40 + 8 * lg];
#pragma unroll
    for (int n = 0; n < 4; n++)
      bf[n] = *(const bf16x8*)&lsb[(wc * 64 + n * 16 + l15) * 40 + 8 * lg];
#pragma unroll
    for (int m = 0; m < WM; m++)
#pragma unroll
      for (int n = 0; n < 4; n++)
        acc[m][n] = mfma16(af[m], bf[n], acc[m][n]);
  }

#pragma unroll
  for (int m = 0; m < WM; m++) {
    int row = m0 + wr * (BM / 2) + m * 16 + lg * 4;
#pragma unroll
    for (int n = 0; n < 4; n++) {
      int col = n0 + wc * 64 + n * 16 + l15;
      float bias = S.bias[col];
#pragma unroll
      for (int r = 0; r < 4; r++) {
        float v = acc[m][n][r] + bias;
        size_t idx = (size_t)(row + r) * N + col;
        if (EPI == 0) {
          S.out[idx] = f2bf(v);
        } else if (EPI == 1) {
          outF[idx] = v + resid[idx];
        } else {
          float gel = 0.5f * v * (1.0f + erff(v * 0.70710678118f));
          S.out[idx] = f2bf(gel);
        }
      }
    }
  }
}

// ---------------- Flash attention ----------------
// q,k [4096, 1024] bf16 (col = h*64+c), vt [32][64][2048] bf16, o [4096,1024] bf16
__global__ __launch_bounds__(256) void attn_kernel(const u16* __restrict__ q,
                                                   const u16* __restrict__ k,
                                                   const u16* __restrict__ vt,
                                                   u16* __restrict__ o) {
  __shared__ u16 pls[4][16 * 72];
  int qb = blockIdx.x, bh = blockIdx.y;
  int b = bh >> 4, h = bh & 15;
  int t = threadIdx.x, w = t >> 6, l = t & 63, l15 = l & 15, lg = l >> 4;
  int qrow = b * LSEQ + qb * 64 + w * 16;
  const u16* qp = q + (size_t)(qrow + l15) * DIM + h * HD;
  bf16x8 av0 = *(const bf16x8*)(qp + 8 * lg);
  bf16x8 av1 = *(const bf16x8*)(qp + 32 + 8 * lg);
  const u16* kb  = k + (size_t)(b * LSEQ) * DIM + h * HD;
  const u16* vtb = vt + (size_t)bh * HD * LSEQ;
  u16* pw = &pls[w][0];

  f32x4 oacc[4];
#pragma unroll
  for (int cb = 0; cb < 4; cb++) oacc[cb] = (f32x4){0.f, 0.f, 0.f, 0.f};
  float mrun[4] = {-1e30f, -1e30f, -1e30f, -1e30f};
  float lsum[4] = {0.f, 0.f, 0.f, 0.f};

  for (int jt = 0; jt < LSEQ; jt += 64) {
    f32x4 s[4];
#pragma unroll
    for (int cb = 0; cb < 4; cb++) s[cb] = (f32x4){0.f, 0.f, 0.f, 0.f};
#pragma unroll
    for (int cb = 0; cb < 4; cb++) {
      const u16* kp = kb + (size_t)(jt + cb * 16 + l15) * DIM;
      bf16x8 b0 = *(const bf16x8*)(kp + 8 * lg);
      bf16x8 b1 = *(const bf16x8*)(kp + 32 + 8 * lg);
      s[cb] = mfma16(av0, b0, s[cb]);
      s[cb] = mfma16(av1, b1, s[cb]);
    }
    // online softmax over keys (cols spread across the 16 lanes of the lg-group)
    float vmax[4], psum[4], scl[4];
#pragma unroll
    for (int r = 0; r < 4; r++)
      vmax[r] = fmaxf(fmaxf(s[0][r], s[1][r]), fmaxf(s[2][r], s[3][r]));
#pragma unroll
    for (int mk = 8; mk >= 1; mk >>= 1)
#pragma unroll
      for (int r = 0; r < 4; r++) vmax[r] = fmaxf(vmax[r], __shfl_xor(vmax[r], mk));
    float p[4][4];
#pragma unroll
    for (int r = 0; r < 4; r++) {
      float mn = fmaxf(mrun[r], SCALE * vmax[r]);
      scl[r] = __expf(mrun[r] - mn);
      mrun[r] = mn;
      float ps = 0.f;
#pragma unroll
      for (int cb = 0; cb < 4; cb++) {
        p[cb][r] = __expf(SCALE * s[cb][r] - mn);
        ps += p[cb][r];
      }
      psum[r] = ps;
    }
#pragma unroll
    for (int mk = 8; mk >= 1; mk >>= 1)
#pragma unroll
      for (int r = 0; r < 4; r++) psum[r] += __shfl_xor(psum[r], mk);
#pragma unroll
    for (int r = 0; r < 4; r++) lsum[r] = lsum[r] * scl[r] + psum[r];
#pragma unroll
    for (int cb = 0; cb < 4; cb++)
#pragma unroll
      for (int r = 0; r < 4; r++) oacc[cb][r] *= scl[r];
    // P -> LDS (re-shape to A-fragment layout)
#pragma unroll
    for (int cb = 0; cb < 4; cb++)
#pragma unroll
      for (int r = 0; r < 4; r++)
        pw[(lg * 4 + r) * 72 + cb * 16 + l15] = f2bf(p[cb][r]);
    // PV
#pragma unroll
    for (int kt = 0; kt < 2; kt++) {
      bf16x8 pa = *(const bf16x8*)&pw[l15 * 72 + kt * 32 + 8 * lg];
#pragma unroll
      for (int cb = 0; cb < 4; cb++) {
        const u16* vp = vtb + (size_t)(cb * 16 + l15) * LSEQ + jt + kt * 32 + 8 * lg;
        bf16x8 vb = *(const bf16x8*)vp;
        oacc[cb] = mfma16(pa, vb, oacc[cb]);
      }
    }
  }
#pragma unroll
  for (int cb = 0; cb < 4; cb++)
#pragma unroll
    for (int r = 0; r < 4; r++) {
      float val = oacc[cb][r] / lsum[r];
      o[(size_t)(qrow + lg * 4 + r) * DIM + h * HD + cb * 16 + l15] = f2bf(val);
    }
}

extern "C" void kernel_launch(void* const* d_in, const int* in_sizes, int n_in,
                              void* d_out, int out_size, void* d_ws, size_t ws_size,
                              hipStream_t stream) {
  const float* x   = (const float*)d_in[0];
  const float* g1  = (const float*)d_in[1];
  const float* b1  = (const float*)d_in[2];
  const float* Wq  = (const float*)d_in[3];
  const float* bq  = (const float*)d_in[4];
  const float* Wk  = (const float*)d_in[5];
  const float* bk  = (const float*)d_in[6];
  const float* Wv  = (const float*)d_in[7];
  const float* bv  = (const float*)d_in[8];
  const float* Wo  = (const float*)d_in[9];
  const float* bo  = (const float*)d_in[10];
  const float* g2  = (const float*)d_in[11];
  const float* b2  = (const float*)d_in[12];
  const float* W1  = (const float*)d_in[13];
  const float* bf1 = (const float*)d_in[14];
  const float* W2  = (const float*)d_in[15];
  const float* bf2 = (const float*)d_in[16];
  float* out = (float*)d_out;

  const size_t E = (size_t)BTOK * DIM;  // 4M elems
  u16* h    = (u16*)d_ws;
  u16* qb   = h + E;
  u16* kbuf = qb + E;
  u16* vbuf = kbuf + E;
  u16* vtb  = vbuf + E;
  float* x2 = (float*)(vtb + E);
  u16* mid  = qb;    // 32MB alias over q,k,v,vt (dead by FFN1)
  u16* ob   = vbuf;  // attn out aliases v (dead after transpose)
  u16* h2   = h;

  // 1. LN1: x -> h (bf16)
  ln_kernel<<<dim3(BTOK), dim3(256), 0, stream>>>(x, g1, b1, h);
  // 2. fused QKV projections
  {
    WSel s0{Wq, bq, qb}, s1{Wk, bk, kbuf}, s2{Wv, bv, vbuf};
    gemm_kernel<128, 0><<<dim3(24, BTOK / 128), 256, 0, stream>>>(
        h, s0, s1, s2, nullptr, nullptr, DIM, DIM, 8);
  }
  // 3. V transpose
  transpose_v<<<dim3(32, 32), 256, 0, stream>>>(vbuf, vtb);
  // 4. flash attention
  attn_kernel<<<dim3(32, 32), 256, 0, stream>>>(qb, kbuf, vtb, ob);
  // 5. O projection + residual -> x2 (fp32)
  {
    WSel s{Wo, bo, nullptr};
    gemm_kernel<64, 1><<<dim3(8, BTOK / 64), 256, 0, stream>>>(
        ob, s, s, s, x, x2, DIM, DIM, 8);
  }
  // 6. LN2: x2 -> h2 (bf16)
  ln_kernel<<<dim3(BTOK), dim3(256), 0, stream>>>(x2, g2, b2, h2);
  // 7. FFN1 + GELU -> mid (bf16)
  {
    WSel s{W1, bf1, mid};
    gemm_kernel<128, 2><<<dim3(32, BTOK / 128), 256, 0, stream>>>(
        h2, s, s, s, nullptr, nullptr, FFN, DIM, 32);
  }
  // 8. FFN2 + residual -> out (fp32)
  {
    WSel s{W2, bf2, nullptr};
    gemm_kernel<64, 1><<<dim3(8, BTOK / 64), 256, 0, stream>>>(
        mid, s, s, s, x2, out, DIM, FFN, 8);
  }
}

// Round 2
// 329.278 us; speedup vs baseline: 1.5860x; 1.5860x over previous
//
#include <hip/hip_runtime.h>
#include <hip/hip_bf16.h>
#include <math.h>

typedef unsigned short u16;
typedef __attribute__((ext_vector_type(8))) __bf16 bf16x8;
typedef __attribute__((ext_vector_type(4))) float f32x4;

#define DIM   1024
#define LSEQ  2048
#define BTOK  4096
#define HD    64
#define FFN   4096
// 1/sqrt(64) * log2(e), folded into Q at projection time so softmax is pure exp2
#define QSCL  0.18033688011112042f

__device__ __forceinline__ u16 f2bf(float f) {
  unsigned u = __builtin_bit_cast(unsigned, f);
  u += 0x7FFFu + ((u >> 16) & 1u);
  return (u16)(u >> 16);
}
__device__ __forceinline__ unsigned pk2(float a, float b) {
  return (unsigned)f2bf(a) | ((unsigned)f2bf(b) << 16);
}
__device__ __forceinline__ f32x4 mfma16(bf16x8 a, bf16x8 b, f32x4 c) {
  return __builtin_amdgcn_mfma_f32_16x16x32_bf16(a, b, c, 0, 0, 0);
}
__device__ __forceinline__ void gload16(const void* g, void* l) {
  __builtin_amdgcn_global_load_lds((const __attribute__((address_space(1))) char*)g,
                                   (__attribute__((address_space(3))) char*)l, 16, 0, 0);
}

// ---------------- LayerNorm (fp32 in -> bf16 out) ----------------
__global__ __launch_bounds__(256) void ln_kernel(const float* __restrict__ x,
                                                 const float* __restrict__ g,
                                                 const float* __restrict__ bta,
                                                 u16* __restrict__ out) {
  int row = blockIdx.x, t = threadIdx.x;
  const float* xr = x + (size_t)row * DIM;
  float4 xv = *(const float4*)(xr + t * 4);
  float s  = xv.x + xv.y + xv.z + xv.w;
  float ss = xv.x * xv.x + xv.y * xv.y + xv.z * xv.z + xv.w * xv.w;
#pragma unroll
  for (int m = 32; m >= 1; m >>= 1) {
    s  += __shfl_xor(s, m);
    ss += __shfl_xor(ss, m);
  }
  __shared__ float red[8];
  if ((t & 63) == 0) { red[(t >> 6) * 2] = s; red[(t >> 6) * 2 + 1] = ss; }
  __syncthreads();
  s  = red[0] + red[2] + red[4] + red[6];
  ss = red[1] + red[3] + red[5] + red[7];
  float mu  = s * (1.0f / DIM);
  float var = ss * (1.0f / DIM) - mu * mu;
  float rs  = rsqrtf(var + 1e-5f);
  float4 gv = *(const float4*)(g + t * 4);
  float4 bv = *(const float4*)(bta + t * 4);
  uint2 o;
  o.x = pk2((xv.x - mu) * rs * gv.x + bv.x, (xv.y - mu) * rs * gv.y + bv.y);
  o.y = pk2((xv.z - mu) * rs * gv.z + bv.z, (xv.w - mu) * rs * gv.w + bv.w);
  *(uint2*)(out + (size_t)row * DIM + t * 4) = o;
}

// ---------------- weight fp32 -> bf16 conversion ----------------
__global__ __launch_bounds__(256) void wconv(const float* __restrict__ Wq, const float* __restrict__ Wk,
                                             const float* __restrict__ Wv, const float* __restrict__ Wo,
                                             const float* __restrict__ W1, const float* __restrict__ W2,
                                             u16* __restrict__ dst) {
  int b = blockIdx.x;
  const float* s;
  size_t off;
  if (b < 2048) { int r = b >> 9; s = (r == 0 ? Wq : r == 1 ? Wk : r == 2 ? Wv : Wo); off = (size_t)r << 20; b &= 511; }
  else if (b < 4096) { s = W1; off = (size_t)4 << 20; b -= 2048; }
  else { s = W2; off = (size_t)8 << 20; b -= 4096; }
  size_t i = ((size_t)b * 256 + threadIdx.x) * 8;
  float4 f0 = *(const float4*)(s + i), f1 = *(const float4*)(s + i + 4);
  uint4 o = { pk2(f0.x, f0.y), pk2(f0.z, f0.w), pk2(f1.x, f1.y), pk2(f1.z, f1.w) };
  *(uint4*)(dst + off + i) = o;
}
__global__ __launch_bounds__(256) void wconv2(const float* __restrict__ W1, const float* __restrict__ W2,
                                              u16* __restrict__ dst) {
  int b = blockIdx.x;
  const float* s;
  size_t off;
  if (b < 2048) { s = W1; off = 0; } else { s = W2; off = (size_t)4 << 20; b -= 2048; }
  size_t i = ((size_t)b * 256 + threadIdx.x) * 8;
  float4 f0 = *(const float4*)(s + i), f1 = *(const float4*)(s + i + 4);
  uint4 o = { pk2(f0.x, f0.y), pk2(f0.z, f0.w), pk2(f1.x, f1.y), pk2(f1.z, f1.w) };
  *(uint4*)(dst + off + i) = o;
}

// ---------------- V transpose: v[b,l,h,c] -> vt[b,h,c,l] ----------------
__global__ __launch_bounds__(256) void transpose_v(const u16* __restrict__ v,
                                                   u16* __restrict__ vt) {
  __shared__ u16 tls[64][80];
  int jb = blockIdx.x, bh = blockIdx.y, b = bh >> 4, h = bh & 15;
  int t = threadIdx.x;
  int r = t >> 2, seg = t & 3;
  const u16* src = v + (size_t)(b * LSEQ + jb * 64 + r) * DIM + h * HD + seg * 16;
  *(uint4*)&tls[r][seg * 16]     = *(const uint4*)src;
  *(uint4*)&tls[r][seg * 16 + 8] = *(const uint4*)(src + 8);
  __syncthreads();
  int c = t >> 2, jseg = t & 3;
  u16 tmp[16] __attribute__((aligned(16)));
#pragma unroll
  for (int i = 0; i < 16; i++) tmp[i] = tls[jseg * 16 + i][c];
  u16* dst = vt + ((size_t)bh * HD + c) * LSEQ + jb * 64 + jseg * 16;
  *(uint4*)dst       = *(const uint4*)tmp;
  *(uint4*)(dst + 8) = *(const uint4*)(tmp + 8);
}

// ---------------- GEMM (m97 structure): C[M,N] = A[M,K](bf16) @ W[N,K]^T + bias ----------------
// EPI 0: outB = bf16((acc+bias)*oscale); 1: outF = acc+bias+resid (fp32); 2: outB = bf16(gelu(acc+bias))
struct GArg { const u16* Wb; const float* Wf; const float* bias; u16* outB; float oscale; };

template <int BM, int EPI, bool WBF16>
__global__ __launch_bounds__(256) void gemm2(const u16* __restrict__ A,
                                             GArg g0, GArg g1, GArg g2,
                                             const float* __restrict__ resid,
                                             float* __restrict__ outF,
                                             int N, int K, int nbPerW) {
  constexpr int WM = BM / 32;
  __shared__ u16 lsa[BM * 32];
  __shared__ u16 lsb[128 * 32];
  const int t = threadIdx.x;
  const int w = t >> 6, l = t & 63, l15 = l & 15, lg = l >> 4;
  const int wr = w >> 1, wc = w & 1;
  const int sel = blockIdx.x / nbPerW;
  const int nb  = blockIdx.x % nbPerW;
  GArg G = (sel == 0) ? g0 : ((sel == 1) ? g1 : g2);
  const int n0 = nb * 128, m0 = blockIdx.y * BM;

  f32x4 acc[WM][4];
#pragma unroll
  for (int m = 0; m < WM; m++)
#pragma unroll
    for (int n = 0; n < 4; n++) acc[m][n] = (f32x4){0.f, 0.f, 0.f, 0.f};

  // global_load_lds source addressing (dest is linear; source pre-swizzled: chunk ^= (row>>1)&3)
  const int grow = t >> 2;
  const int gcol = 8 * ((t & 3) ^ ((t >> 3) & 3));
  const u16* Asrc = A + (size_t)(m0 + grow) * K + gcol;
  const u16* Bsrc = WBF16 ? G.Wb + (size_t)(n0 + grow) * K + gcol : nullptr;
  const int brow = t >> 1, bh2 = t & 1, bsw = (t >> 2) & 3;
  const float* Wfp = WBF16 ? nullptr : G.Wf + (size_t)(n0 + brow) * K + bh2 * 16;
  const int rs = (l15 >> 1) & 3;  // read-side swizzle

  for (int k0 = 0; k0 < K; k0 += 32) {
    __syncthreads();
#pragma unroll
    for (int ia = 0; ia < BM / 64; ia++)
      gload16(Asrc + (size_t)ia * 64 * K + k0, (char*)lsa + ia * 4096 + w * 1024);
    if (WBF16) {
#pragma unroll
      for (int ib = 0; ib < 2; ib++)
        gload16(Bsrc + (size_t)ib * 64 * K + k0, (char*)lsb + ib * 4096 + w * 1024);
    } else {
      const float* wp = Wfp + k0;
      float4 f0 = *(const float4*)(wp);
      float4 f1 = *(const float4*)(wp + 4);
      float4 f2 = *(const float4*)(wp + 8);
      float4 f3 = *(const float4*)(wp + 12);
      uint4 plo = { pk2(f0.x, f0.y), pk2(f0.z, f0.w), pk2(f1.x, f1.y), pk2(f1.z, f1.w) };
      uint4 phi = { pk2(f2.x, f2.y), pk2(f2.z, f2.w), pk2(f3.x, f3.y), pk2(f3.z, f3.w) };
      *(uint4*)&lsb[brow * 32 + ((bh2 * 2)     ^ bsw) * 8] = plo;
      *(uint4*)&lsb[brow * 32 + ((bh2 * 2 + 1) ^ bsw) * 8] = phi;
    }
    __syncthreads();

    bf16x8 af[WM], bfr[4];
#pragma unroll
    for (int m = 0; m < WM; m++)
      af[m] = *(const bf16x8*)&lsa[(wr * (BM / 2) + m * 16 + l15) * 32 + (lg ^ rs) * 8];
#pragma unroll
    for (int n = 0; n < 4; n++)
      bfr[n] = *(const bf16x8*)&lsb[(wc * 64 + n * 16 + l15) * 32 + (lg ^ rs) * 8];
#pragma unroll
    for (int m = 0; m < WM; m++)
#pragma unroll
      for (int n = 0; n < 4; n++)
        acc[m][n] = mfma16(af[m], bfr[n], acc[m][n]);
  }

#pragma unroll
  for (int m = 0; m < WM; m++) {
    const int row = m0 + wr * (BM / 2) + m * 16 + lg * 4;
#pragma unroll
    for (int n = 0; n < 4; n++) {
      const int col = n0 + wc * 64 + n * 16 + l15;
      const float bias = G.bias[col];
#pragma unroll
      for (int r = 0; r < 4; r++) {
        const float v = acc[m][n][r] + bias;
        const size_t idx = (size_t)(row + r) * N + col;
        if (EPI == 0)      G.outB[idx] = f2bf(v * G.oscale);
        else if (EPI == 1) outF[idx] = v + resid[idx];
        else               G.outB[idx] = f2bf(0.5f * v * (1.0f + erff(v * 0.70710678118f)));
      }
    }
  }
}

// ---------------- Flash attention v2 ----------------
// Swapped QK^T (key axis lane-local), LDS-staged K/V (dbuf, swizzled), 4 waves x 32 q-rows.
// q pre-scaled by SCALE*log2e -> softmax = exp2.
__global__ __launch_bounds__(256) void attn2(const u16* __restrict__ q,
                                             const u16* __restrict__ k,
                                             const u16* __restrict__ vt,
                                             u16* __restrict__ o) {
  __shared__ u16 kls[2][64 * 64];  // [key][c], 16B chunks swizzled: c' = c ^ (row&7)
  __shared__ u16 vls[2][64 * 64];  // [c][key], same swizzle
  __shared__ u16 pls[4][32 * 64];  // per-wave P [q][key], same swizzle
  const int t = threadIdx.x, w = t >> 6, l = t & 63, l15 = l & 15, lg = l >> 4;
  const int qbk = blockIdx.x, bh = blockIdx.y, b = bh >> 4, h = bh & 15;
  const int qrow0 = b * LSEQ + qbk * 128 + w * 32;

  // Q fragments (B-operand): av[m][i] = Q[qrow0+m*16+l15][h*64 + i*32 + lg*8 ..]
  bf16x8 av[2][2];
#pragma unroll
  for (int m = 0; m < 2; m++)
#pragma unroll
    for (int i = 0; i < 2; i++)
      av[m][i] = *(const bf16x8*)(q + (size_t)(qrow0 + m * 16 + l15) * DIM + h * HD + i * 32 + lg * 8);

  // staging source addressing (linear LDS dest, pre-swizzled global source)
  const int grow = t >> 3, gchk = t & 7;
  const u16* ksrc = k + (size_t)(b * LSEQ + grow) * DIM + h * HD + 8 * (gchk ^ (grow & 7));
  const u16* vsrc = vt + ((size_t)bh * HD + grow) * LSEQ + 8 * (gchk ^ (grow & 7));

  f32x4 oacc[2][4];
#pragma unroll
  for (int m = 0; m < 2; m++)
#pragma unroll
    for (int cb = 0; cb < 4; cb++) oacc[m][cb] = (f32x4){0.f, 0.f, 0.f, 0.f};
  float mrun[2] = {-INFINITY, -INFINITY};
  float lsum[2] = {0.f, 0.f};
  u16* pw = &pls[w][0];

  auto issueTile = [&](int jt, int buf) {
    const u16* kp = ksrc + (size_t)jt * DIM;
    const u16* vp = vsrc + jt;
#pragma unroll
    for (int i = 0; i < 2; i++) {
      gload16(kp + (size_t)i * 32 * DIM,  (char*)&kls[buf][0] + i * 4096 + w * 1024);
      gload16(vp + (size_t)i * 32 * LSEQ, (char*)&vls[buf][0] + i * 4096 + w * 1024);
    }
  };

  issueTile(0, 0);
  for (int it = 0; it < LSEQ / 64; it++) {
    const int buf = it & 1;
    __syncthreads();  // drains tile-it loads; all waves done with buf^1
    if (it + 1 < LSEQ / 64) issueTile((it + 1) * 64, buf ^ 1);

    // ---- QK^T (swapped: A=K so keys are lane-local in S) ----
    f32x4 s[2][4];
#pragma unroll
    for (int m = 0; m < 2; m++)
#pragma unroll
      for (int cb = 0; cb < 4; cb++) s[m][cb] = (f32x4){0.f, 0.f, 0.f, 0.f};
    const u16* kb = &kls[buf][0];
    __builtin_amdgcn_s_setprio(1);
#pragma unroll
    for (int i = 0; i < 2; i++) {
#pragma unroll
      for (int cb = 0; cb < 4; cb++) {
        const int krow = cb * 16 + l15;
        bf16x8 kf = *(const bf16x8*)&kb[krow * 64 + (((i << 2) | lg) ^ (krow & 7)) * 8];
        s[0][cb] = mfma16(kf, av[0][i], s[0][cb]);
        s[1][cb] = mfma16(kf, av[1][i], s[1][cb]);
      }
    }
    __builtin_amdgcn_s_setprio(0);

    // ---- online softmax (per lane: one query q = m*16+l15, 16 keys) ----
#pragma unroll
    for (int m = 0; m < 2; m++) {
      float c0 = fmaxf(fmaxf(s[m][0][0], s[m][0][1]), fmaxf(s[m][0][2], s[m][0][3]));
      float c1 = fmaxf(fmaxf(s[m][1][0], s[m][1][1]), fmaxf(s[m][1][2], s[m][1][3]));
      float c2 = fmaxf(fmaxf(s[m][2][0], s[m][2][1]), fmaxf(s[m][2][2], s[m][2][3]));
      float c3 = fmaxf(fmaxf(s[m][3][0], s[m][3][1]), fmaxf(s[m][3][2], s[m][3][3]));
      float tmax = fmaxf(fmaxf(c0, c1), fmaxf(c2, c3));
      tmax = fmaxf(tmax, __shfl_xor(tmax, 16));
      tmax = fmaxf(tmax, __shfl_xor(tmax, 32));
      const float mn = fmaxf(mrun[m], tmax);
      const float scl = exp2f(mrun[m] - mn);
      mrun[m] = mn;
      float p[4][4];
      float ps = 0.f;
#pragma unroll
      for (int cb = 0; cb < 4; cb++) {
        float a0 = exp2f(s[m][cb][0] - mn);
        float a1 = exp2f(s[m][cb][1] - mn);
        float a2 = exp2f(s[m][cb][2] - mn);
        float a3 = exp2f(s[m][cb][3] - mn);
        p[cb][0] = a0; p[cb][1] = a1; p[cb][2] = a2; p[cb][3] = a3;
        ps += (a0 + a1) + (a2 + a3);
      }
      ps += __shfl_xor(ps, 16);
      ps += __shfl_xor(ps, 32);
      lsum[m] = lsum[m] * scl + ps;
      // broadcast scl from softmax layout (q=l15) to accumulator layout (q=lg*4+r)
#pragma unroll
      for (int r = 0; r < 4; r++) {
        const float so = __shfl(scl, lg * 4 + r);
#pragma unroll
        for (int cb = 0; cb < 4; cb++) oacc[m][cb][r] *= so;
      }
      // P -> LDS (swizzled), bf16
      const int prow = m * 16 + l15;
#pragma unroll
      for (int cb = 0; cb < 4; cb++) {
        const int c = 2 * cb + (lg >> 1);
        const int byteoff = prow * 128 + ((c ^ (l15 & 7)) * 16) + (lg & 1) * 8;
        uint2 pkv;
        pkv.x = pk2(p[cb][0], p[cb][1]);
        pkv.y = pk2(p[cb][2], p[cb][3]);
        *(uint2*)((char*)pw + byteoff) = pkv;
      }
    }

    // ---- PV ----
    const u16* vb = &vls[buf][0];
#pragma unroll
    for (int kt = 0; kt < 2; kt++) {
      bf16x8 pa[2];
#pragma unroll
      for (int m = 0; m < 2; m++) {
        const int prow = m * 16 + l15;
        pa[m] = *(const bf16x8*)((char*)pw + prow * 128 + (((4 * kt + lg) ^ (l15 & 7)) * 16));
      }
      __builtin_amdgcn_s_setprio(1);
#pragma unroll
      for (int cb = 0; cb < 4; cb++) {
        const int vrow = cb * 16 + l15;
        bf16x8 vf = *(const bf16x8*)&vb[vrow * 64 + (((kt << 2) | lg) ^ (vrow & 7)) * 8];
        oacc[0][cb] = mfma16(pa[0], vf, oacc[0][cb]);
        oacc[1][cb] = mfma16(pa[1], vf, oacc[1][cb]);
      }
      __builtin_amdgcn_s_setprio(0);
    }
  }

  // epilogue: O = oacc / lsum (broadcast lsum to accumulator layout)
#pragma unroll
  for (int m = 0; m < 2; m++) {
#pragma unroll
    for (int r = 0; r < 4; r++) {
      const float lo = __shfl(lsum[m], lg * 4 + r);
      const float rcp = 1.0f / lo;
#pragma unroll
      for (int cb = 0; cb < 4; cb++) {
        o[(size_t)(qrow0 + m * 16 + lg * 4 + r) * DIM + h * HD + cb * 16 + l15] =
            f2bf(oacc[m][cb][r] * rcp);
      }
    }
  }
}

extern "C" void kernel_launch(void* const* d_in, const int* in_sizes, int n_in,
                              void* d_out, int out_size, void* d_ws, size_t ws_size,
                              hipStream_t stream) {
  const float* x   = (const float*)d_in[0];
  const float* g1  = (const float*)d_in[1];
  const float* b1  = (const float*)d_in[2];
  const float* Wq  = (const float*)d_in[3];
  const float* bq  = (const float*)d_in[4];
  const float* Wk  = (const float*)d_in[5];
  const float* bk  = (const float*)d_in[6];
  const float* Wv  = (const float*)d_in[7];
  const float* bv  = (const float*)d_in[8];
  const float* Wo  = (const float*)d_in[9];
  const float* bo  = (const float*)d_in[10];
  const float* g2  = (const float*)d_in[11];
  const float* b2  = (const float*)d_in[12];
  const float* W1  = (const float*)d_in[13];
  const float* bf1 = (const float*)d_in[14];
  const float* W2  = (const float*)d_in[15];
  const float* bf2 = (const float*)d_in[16];
  float* out = (float*)d_out;

  const size_t E = (size_t)BTOK * DIM;  // 4M elems
  u16* h     = (u16*)d_ws;
  u16* qb    = h + E;
  u16* kbuf  = qb + E;
  u16* vbuf  = kbuf + E;
  u16* vtb   = vbuf + E;
  u16* wbase = vtb + E;          // bf16 weights (full: 12M elems = 24MB; fallback: 8M = 16MB)
  u16* mid   = qb;               // 32MB alias over q,k,v,vt (dead by FFN1)
  u16* ob    = vbuf;             // attn out aliases v (dead after transpose)
  u16* h2    = h;
  float* x2  = out;              // attention residual lives in d_out (fp32)

  const bool full = ws_size >= (size_t)(64ull << 20);  // 40MB bufs + 24MB weights

  // 0. weights -> bf16
  if (full) {
    wconv<<<dim3(6144), dim3(256), 0, stream>>>(Wq, Wk, Wv, Wo, W1, W2, wbase);
  } else {
    wconv2<<<dim3(4096), dim3(256), 0, stream>>>(W1, W2, wbase);
  }
  u16* Wqb = wbase;
  u16* Wkb = wbase + ((size_t)1 << 20);
  u16* Wvb = wbase + ((size_t)2 << 20);
  u16* Wob = wbase + ((size_t)3 << 20);
  u16* W1b = full ? wbase + ((size_t)4 << 20) : wbase;
  u16* W2b = full ? wbase + ((size_t)8 << 20) : wbase + ((size_t)4 << 20);

  // 1. LN1: x -> h (bf16)
  ln_kernel<<<dim3(BTOK), dim3(256), 0, stream>>>(x, g1, b1, h);

  // 2. fused QKV projections (q pre-scaled by SCALE*log2e)
  if (full) {
    gemm2<128, 0, true><<<dim3(24, BTOK / 128), 256, 0, stream>>>(
        h, GArg{Wqb, nullptr, bq, qb, QSCL}, GArg{Wkb, nullptr, bk, kbuf, 1.0f},
        GArg{Wvb, nullptr, bv, vbuf, 1.0f}, nullptr, nullptr, DIM, DIM, 8);
  } else {
    gemm2<128, 0, false><<<dim3(24, BTOK / 128), 256, 0, stream>>>(
        h, GArg{nullptr, Wq, bq, qb, QSCL}, GArg{nullptr, Wk, bk, kbuf, 1.0f},
        GArg{nullptr, Wv, bv, vbuf, 1.0f}, nullptr, nullptr, DIM, DIM, 8);
  }

  // 3. V transpose
  transpose_v<<<dim3(32, 32), 256, 0, stream>>>(vbuf, vtb);

  // 4. flash attention
  attn2<<<dim3(LSEQ / 128, 32), 256, 0, stream>>>(qb, kbuf, vtb, ob);

  // 5. O projection + residual -> x2 (= d_out, fp32)
  if (full) {
    GArg s{Wob, nullptr, bo, nullptr, 1.0f};
    gemm2<64, 1, true><<<dim3(8, BTOK / 64), 256, 0, stream>>>(
        ob, s, s, s, x, x2, DIM, DIM, 8);
  } else {
    GArg s{nullptr, Wo, bo, nullptr, 1.0f};
    gemm2<64, 1, false><<<dim3(8, BTOK / 64), 256, 0, stream>>>(
        ob, s, s, s, x, x2, DIM, DIM, 8);
  }

  // 6. LN2: x2 -> h2 (bf16)
  ln_kernel<<<dim3(BTOK), dim3(256), 0, stream>>>(x2, g2, b2, h2);

  // 7. FFN1 + GELU -> mid (bf16)
  {
    GArg s{W1b, nullptr, bf1, mid, 1.0f};
    gemm2<128, 2, true><<<dim3(32, BTOK / 128), 256, 0, stream>>>(
        h2, s, s, s, nullptr, nullptr, FFN, DIM, 32);
  }
  // 8. FFN2 + residual (in-place on d_out)
  {
    GArg s{W2b, nullptr, bf2, nullptr, 1.0f};
    gemm2<64, 1, true><<<dim3(8, BTOK / 64), 256, 0, stream>>>(
        mid, s, s, s, x2, out, DIM, FFN, 8);
  }
}

// Round 3
// 310.068 us; speedup vs baseline: 1.6843x; 1.0620x over previous
//
#include <hip/hip_runtime.h>
#include <hip/hip_bf16.h>
#include <math.h>

typedef unsigned short u16;
typedef __attribute__((ext_vector_type(8))) __bf16 bf16x8;
typedef __attribute__((ext_vector_type(4))) float f32x4;

#define DIM   1024
#define LSEQ  2048
#define BTOK  4096
#define HD    64
#define FFN   4096
// 1/sqrt(64) * log2(e), folded into Q at projection time so softmax is pure exp2
#define QSCL  0.18033688011112042f

__device__ __forceinline__ u16 f2bf(float f) {
  unsigned u = __builtin_bit_cast(unsigned, f);
  u += 0x7FFFu + ((u >> 16) & 1u);
  return (u16)(u >> 16);
}
__device__ __forceinline__ unsigned pk2(float a, float b) {
  return (unsigned)f2bf(a) | ((unsigned)f2bf(b) << 16);
}
__device__ __forceinline__ unsigned cvtpk(float lo, float hi) {
  unsigned r;
  asm("v_cvt_pk_bf16_f32 %0, %1, %2" : "=v"(r) : "v"(lo), "v"(hi));
  return r;
}
__device__ __forceinline__ f32x4 mfma16(bf16x8 a, bf16x8 b, f32x4 c) {
  return __builtin_amdgcn_mfma_f32_16x16x32_bf16(a, b, c, 0, 0, 0);
}
__device__ __forceinline__ void gload16(const void* g, void* l) {
  __builtin_amdgcn_global_load_lds((const __attribute__((address_space(1))) char*)g,
                                   (__attribute__((address_space(3))) char*)l, 16, 0, 0);
}

// ---------------- LayerNorm (fp32 in -> bf16 out) ----------------
__global__ __launch_bounds__(256) void ln_kernel(const float* __restrict__ x,
                                                 const float* __restrict__ g,
                                                 const float* __restrict__ bta,
                                                 u16* __restrict__ out) {
  int row = blockIdx.x, t = threadIdx.x;
  const float* xr = x + (size_t)row * DIM;
  float4 xv = *(const float4*)(xr + t * 4);
  float s  = xv.x + xv.y + xv.z + xv.w;
  float ss = xv.x * xv.x + xv.y * xv.y + xv.z * xv.z + xv.w * xv.w;
#pragma unroll
  for (int m = 32; m >= 1; m >>= 1) {
    s  += __shfl_xor(s, m);
    ss += __shfl_xor(ss, m);
  }
  __shared__ float red[8];
  if ((t & 63) == 0) { red[(t >> 6) * 2] = s; red[(t >> 6) * 2 + 1] = ss; }
  __syncthreads();
  s  = red[0] + red[2] + red[4] + red[6];
  ss = red[1] + red[3] + red[5] + red[7];
  float mu  = s * (1.0f / DIM);
  float var = ss * (1.0f / DIM) - mu * mu;
  float rs  = rsqrtf(var + 1e-5f);
  float4 gv = *(const float4*)(g + t * 4);
  float4 bv = *(const float4*)(bta + t * 4);
  uint2 o;
  o.x = pk2((xv.x - mu) * rs * gv.x + bv.x, (xv.y - mu) * rs * gv.y + bv.y);
  o.y = pk2((xv.z - mu) * rs * gv.z + bv.z, (xv.w - mu) * rs * gv.w + bv.w);
  *(uint2*)(out + (size_t)row * DIM + t * 4) = o;
}

// ---------------- weight fp32 -> bf16 ----------------
__global__ __launch_bounds__(256) void wcvt4(const float* __restrict__ Wq, const float* __restrict__ Wk,
                                             const float* __restrict__ Wv, const float* __restrict__ Wo,
                                             u16* __restrict__ dst) {
  int b = blockIdx.x;
  int r = b >> 9;
  const float* s = (r == 0) ? Wq : (r == 1) ? Wk : (r == 2) ? Wv : Wo;
  size_t i = (((size_t)(b & 511)) * 256 + threadIdx.x) * 8;
  float4 f0 = *(const float4*)(s + i), f1 = *(const float4*)(s + i + 4);
  uint4 o = { pk2(f0.x, f0.y), pk2(f0.z, f0.w), pk2(f1.x, f1.y), pk2(f1.z, f1.w) };
  *(uint4*)(dst + ((size_t)r << 20) + i) = o;
}
__global__ __launch_bounds__(256) void wcvt2(const float* __restrict__ W1, const float* __restrict__ W2,
                                             u16* __restrict__ d1, u16* __restrict__ d2) {
  int b = blockIdx.x;
  const float* s = (b < 2048) ? W1 : W2;
  u16* d = (b < 2048) ? d1 : d2;
  size_t i = (((size_t)(b & 2047)) * 256 + threadIdx.x) * 8;
  float4 f0 = *(const float4*)(s + i), f1 = *(const float4*)(s + i + 4);
  uint4 o = { pk2(f0.x, f0.y), pk2(f0.z, f0.w), pk2(f1.x, f1.y), pk2(f1.z, f1.w) };
  *(uint4*)(d + i) = o;
}

// ---------------- V transpose: v[b,l,h,c] -> vt[b,h,c,l] ----------------
__global__ __launch_bounds__(256) void transpose_v(const u16* __restrict__ v,
                                                   u16* __restrict__ vt) {
  __shared__ u16 tls[64][80];
  int jb = blockIdx.x, bh = blockIdx.y, b = bh >> 4, h = bh & 15;
  int t = threadIdx.x;
  int r = t >> 2, seg = t & 3;
  const u16* src = v + (size_t)(b * LSEQ + jb * 64 + r) * DIM + h * HD + seg * 16;
  *(uint4*)&tls[r][seg * 16]     = *(const uint4*)src;
  *(uint4*)&tls[r][seg * 16 + 8] = *(const uint4*)(src + 8);
  __syncthreads();
  int c = t >> 2, jseg = t & 3;
  u16 tmp[16] __attribute__((aligned(16)));
#pragma unroll
  for (int i = 0; i < 16; i++) tmp[i] = tls[jseg * 16 + i][c];
  u16* dst = vt + ((size_t)bh * HD + c) * LSEQ + jb * 64 + jseg * 16;
  *(uint4*)dst       = *(const uint4*)tmp;
  *(uint4*)(dst + 8) = *(const uint4*)(tmp + 8);
}

// ---------------- GEMM (2-phase dbuf, BM=BN=128): C = A(bf16) @ W(bf16,[N,K])^T + bias ----------------
// EPI 0: outB = bf16((acc+bias)*oscale); 1: outF = acc+bias+resid (fp32); 2: outB = bf16(gelu(acc+bias))
struct GArg { const u16* Wb; const float* bias; u16* outB; float oscale; };

template <int EPI>
__global__ __launch_bounds__(256) void gemm3(const u16* __restrict__ A,
                                             GArg g0, GArg g1, GArg g2,
                                             const float* __restrict__ resid,
                                             float* __restrict__ outF,
                                             int N, int K, int nbPerW) {
  __shared__ u16 lsa[2][128 * 32];
  __shared__ u16 lsb[2][128 * 32];
  const int t = threadIdx.x;
  const int w = t >> 6, l = t & 63, l15 = l & 15, lg = l >> 4;
  const int wr = w >> 1, wc = w & 1;
  // bijective XCD-chunk remap (all launch grids have nwg % 8 == 0)
  const int nwg = gridDim.x * gridDim.y;
  int flat = blockIdx.y * gridDim.x + blockIdx.x;
  flat = (flat & 7) * (nwg >> 3) + (flat >> 3);
  const int bx = flat % gridDim.x, by = flat / gridDim.x;
  const int sel = bx / nbPerW, nb = bx % nbPerW;
  GArg G = (sel == 0) ? g0 : ((sel == 1) ? g1 : g2);
  const int n0 = nb * 128, m0 = by * 128;

  f32x4 acc[4][4];
#pragma unroll
  for (int m = 0; m < 4; m++)
#pragma unroll
    for (int n = 0; n < 4; n++) acc[m][n] = (f32x4){0.f, 0.f, 0.f, 0.f};

  // staging: linear LDS dest, pre-swizzled global source (chunk ^= (row>>1)&3)
  const int grow = t >> 2;
  const int gcol = 8 * ((t & 3) ^ ((t >> 3) & 3));
  const u16* Asrc = A + (size_t)(m0 + grow) * K + gcol;
  const u16* Bsrc = G.Wb + (size_t)(n0 + grow) * K + gcol;
  const int rs = (l15 >> 1) & 3;  // read-side swizzle key

  auto stage = [&](int k0, int buf) {
#pragma unroll
    for (int i = 0; i < 2; i++) {
      gload16(Asrc + (size_t)i * 64 * K + k0, (char*)lsa + buf * 8192 + i * 4096 + w * 1024);
      gload16(Bsrc + (size_t)i * 64 * K + k0, (char*)lsb + buf * 8192 + i * 4096 + w * 1024);
    }
  };

  stage(0, 0);
  const int NT = K >> 5;
  for (int it = 0; it < NT; it++) {
    const int buf = it & 1;
    __syncthreads();                       // implicit vmcnt(0)+lgkmcnt(0): tile `it` ready
    if (it + 1 < NT) stage((it + 1) << 5, buf ^ 1);  // hides under this tile's compute

    bf16x8 af[4], bfr[4];
#pragma unroll
    for (int m = 0; m < 4; m++)
      af[m] = *(const bf16x8*)&lsa[buf][(wr * 64 + m * 16 + l15) * 32 + (lg ^ rs) * 8];
#pragma unroll
    for (int n = 0; n < 4; n++)
      bfr[n] = *(const bf16x8*)&lsb[buf][(wc * 64 + n * 16 + l15) * 32 + (lg ^ rs) * 8];
#pragma unroll
    for (int m = 0; m < 4; m++)
#pragma unroll
      for (int n = 0; n < 4; n++)
        acc[m][n] = mfma16(af[m], bfr[n], acc[m][n]);
  }

#pragma unroll
  for (int m = 0; m < 4; m++) {
    const int row = m0 + wr * 64 + m * 16 + lg * 4;
#pragma unroll
    for (int n = 0; n < 4; n++) {
      const int col = n0 + wc * 64 + n * 16 + l15;
      const float bias = G.bias[col];
#pragma unroll
      for (int r = 0; r < 4; r++) {
        const float v = acc[m][n][r] + bias;
        const size_t idx = (size_t)(row + r) * N + col;
        if (EPI == 0)      G.outB[idx] = f2bf(v * G.oscale);
        else if (EPI == 1) outF[idx] = v + resid[idx];
        else               G.outB[idx] = f2bf(0.5f * v * (1.0f + erff(v * 0.70710678118f)));
      }
    }
  }
}

// ---------------- Flash attention v3 ----------------
// Swapped QK^T (keys lane-local), LDS dbuf K/V (swizzled), cvt_pk P-pack, defer-rescale.
__global__ __launch_bounds__(256) void attn3(const u16* __restrict__ q,
                                             const u16* __restrict__ k,
                                             const u16* __restrict__ vt,
                                             u16* __restrict__ o) {
  __shared__ u16 kls[2][64 * 64];  // [key][c], 16B chunks swizzled: c' = c ^ (row&7)
  __shared__ u16 vls[2][64 * 64];  // [c][key], same swizzle
  __shared__ u16 pls[4][32 * 64];  // per-wave P [q][key], same swizzle
  const int t = threadIdx.x, w = t >> 6, l = t & 63, l15 = l & 15, lg = l >> 4;
  const int qbk = blockIdx.x, bh = blockIdx.y, b = bh >> 4, h = bh & 15;
  const int qrow0 = b * LSEQ + qbk * 128 + w * 32;

  bf16x8 av[2][2];
#pragma unroll
  for (int m = 0; m < 2; m++)
#pragma unroll
    for (int i = 0; i < 2; i++)
      av[m][i] = *(const bf16x8*)(q + (size_t)(qrow0 + m * 16 + l15) * DIM + h * HD + i * 32 + lg * 8);

  const int grow = t >> 3, gchk = t & 7;
  const u16* ksrc = k + (size_t)(b * LSEQ + grow) * DIM + h * HD + 8 * (gchk ^ (grow & 7));
  const u16* vsrc = vt + ((size_t)bh * HD + grow) * LSEQ + 8 * (gchk ^ (grow & 7));

  f32x4 oacc[2][4];
#pragma unroll
  for (int m = 0; m < 2; m++)
#pragma unroll
    for (int cb = 0; cb < 4; cb++) oacc[m][cb] = (f32x4){0.f, 0.f, 0.f, 0.f};
  float mrun[2] = {-INFINITY, -INFINITY};
  float lsum[2] = {0.f, 0.f};
  u16* pw = &pls[w][0];

  auto issueTile = [&](int jt, int buf) {
    const u16* kp = ksrc + (size_t)jt * DIM;
    const u16* vp = vsrc + jt;
#pragma unroll
    for (int i = 0; i < 2; i++) {
      gload16(kp + (size_t)i * 32 * DIM,  (char*)&kls[buf][0] + i * 4096 + w * 1024);
      gload16(vp + (size_t)i * 32 * LSEQ, (char*)&vls[buf][0] + i * 4096 + w * 1024);
    }
  };

  issueTile(0, 0);
  for (int it = 0; it < LSEQ / 64; it++) {
    const int buf = it & 1;
    __syncthreads();
    if (it + 1 < LSEQ / 64) issueTile((it + 1) * 64, buf ^ 1);

    // ---- QK^T ----
    f32x4 s[2][4];
#pragma unroll
    for (int m = 0; m < 2; m++)
#pragma unroll
      for (int cb = 0; cb < 4; cb++) s[m][cb] = (f32x4){0.f, 0.f, 0.f, 0.f};
    const u16* kb = &kls[buf][0];
    __builtin_amdgcn_s_setprio(1);
#pragma unroll
    for (int i = 0; i < 2; i++) {
#pragma unroll
      for (int cb = 0; cb < 4; cb++) {
        const int krow = cb * 16 + l15;
        bf16x8 kf = *(const bf16x8*)&kb[krow * 64 + (((i << 2) | lg) ^ (krow & 7)) * 8];
        s[0][cb] = mfma16(kf, av[0][i], s[0][cb]);
        s[1][cb] = mfma16(kf, av[1][i], s[1][cb]);
      }
    }
    __builtin_amdgcn_s_setprio(0);

    // ---- online softmax: lane owns q = m*16+l15, keys cb*16+lg*4+r ----
    float tmax[2];
#pragma unroll
    for (int m = 0; m < 2; m++) {
      float a = fmaxf(fmaxf(s[m][0][0], s[m][0][1]), fmaxf(s[m][0][2], s[m][0][3]));
      float c = fmaxf(fmaxf(s[m][1][0], s[m][1][1]), fmaxf(s[m][1][2], s[m][1][3]));
      float d = fmaxf(fmaxf(s[m][2][0], s[m][2][1]), fmaxf(s[m][2][2], s[m][2][3]));
      float e = fmaxf(fmaxf(s[m][3][0], s[m][3][1]), fmaxf(s[m][3][2], s[m][3][3]));
      float tm = fmaxf(fmaxf(a, c), fmaxf(d, e));
      tm = fmaxf(tm, __shfl_xor(tm, 16));
      tm = fmaxf(tm, __shfl_xor(tm, 32));
      tmax[m] = tm;
    }
    // defer-rescale: only pay the rescale when the running max grows by > 8 (log2 units)
    bool need = (tmax[0] > mrun[0] + 8.0f) || (tmax[1] > mrun[1] + 8.0f);
    if (__any(need)) {
#pragma unroll
      for (int m = 0; m < 2; m++) {
        const float mn = fmaxf(mrun[m], tmax[m]);
        const float scl = exp2f(mrun[m] - mn);
        mrun[m] = mn;
        lsum[m] *= scl;
#pragma unroll
        for (int r = 0; r < 4; r++) {
          const float so = __shfl(scl, lg * 4 + r);
#pragma unroll
          for (int cb = 0; cb < 4; cb++) oacc[m][cb][r] *= so;
        }
      }
    }
#pragma unroll
    for (int m = 0; m < 2; m++) {
      float ps = 0.f;
      uint2 pk[4];
#pragma unroll
      for (int cb = 0; cb < 4; cb++) {
        float a0 = exp2f(s[m][cb][0] - mrun[m]);
        float a1 = exp2f(s[m][cb][1] - mrun[m]);
        float a2 = exp2f(s[m][cb][2] - mrun[m]);
        float a3 = exp2f(s[m][cb][3] - mrun[m]);
        ps += (a0 + a1) + (a2 + a3);
        pk[cb].x = cvtpk(a0, a1);
        pk[cb].y = cvtpk(a2, a3);
      }
      ps += __shfl_xor(ps, 16);
      ps += __shfl_xor(ps, 32);
      lsum[m] += ps;
      const int prow = m * 16 + l15;
#pragma unroll
      for (int cb = 0; cb < 4; cb++) {
        const int c = 2 * cb + (lg >> 1);
        *(uint2*)((char*)pw + prow * 128 + ((c ^ (l15 & 7)) * 16) + (lg & 1) * 8) = pk[cb];
      }
    }

    // ---- PV ----
    const u16* vb = &vls[buf][0];
#pragma unroll
    for (int kt = 0; kt < 2; kt++) {
      bf16x8 pa[2];
#pragma unroll
      for (int m = 0; m < 2; m++) {
        const int prow = m * 16 + l15;
        pa[m] = *(const bf16x8*)((char*)pw + prow * 128 + (((4 * kt + lg) ^ (l15 & 7)) * 16));
      }
      __builtin_amdgcn_s_setprio(1);
#pragma unroll
      for (int cb = 0; cb < 4; cb++) {
        const int vrow = cb * 16 + l15;
        bf16x8 vf = *(const bf16x8*)&vb[vrow * 64 + (((kt << 2) | lg) ^ (vrow & 7)) * 8];
        oacc[0][cb] = mfma16(pa[0], vf, oacc[0][cb]);
        oacc[1][cb] = mfma16(pa[1], vf, oacc[1][cb]);
      }
      __builtin_amdgcn_s_setprio(0);
    }
  }

#pragma unroll
  for (int m = 0; m < 2; m++) {
#pragma unroll
    for (int r = 0; r < 4; r++) {
      const float lo = __shfl(lsum[m], lg * 4 + r);
      const float rcp = 1.0f / lo;
#pragma unroll
      for (int cb = 0; cb < 4; cb++) {
        o[(size_t)(qrow0 + m * 16 + lg * 4 + r) * DIM + h * HD + cb * 16 + l15] =
            f2bf(oacc[m][cb][r] * rcp);
      }
    }
  }
}

extern "C" void kernel_launch(void* const* d_in, const int* in_sizes, int n_in,
                              void* d_out, int out_size, void* d_ws, size_t ws_size,
                              hipStream_t stream) {
  const float* x   = (const float*)d_in[0];
  const float* g1  = (const float*)d_in[1];
  const float* b1  = (const float*)d_in[2];
  const float* Wq  = (const float*)d_in[3];
  const float* bq  = (const float*)d_in[4];
  const float* Wk  = (const float*)d_in[5];
  const float* bk  = (const float*)d_in[6];
  const float* Wv  = (const float*)d_in[7];
  const float* bv  = (const float*)d_in[8];
  const float* Wo  = (const float*)d_in[9];
  const float* bo  = (const float*)d_in[10];
  const float* g2  = (const float*)d_in[11];
  const float* b2  = (const float*)d_in[12];
  const float* W1  = (const float*)d_in[13];
  const float* bf1 = (const float*)d_in[14];
  const float* W2  = (const float*)d_in[15];
  const float* bf2 = (const float*)d_in[16];
  float* out = (float*)d_out;

  const size_t E = (size_t)BTOK * DIM;  // 4M elems
  u16* h     = (u16*)d_ws;   // 8MB
  u16* qb    = h + E;
  u16* kbuf  = qb + E;
  u16* vbuf  = kbuf + E;
  u16* vtb   = vbuf + E;
  u16* wqkvo = vtb + E;      // 8MB bf16 Wq|Wk|Wv|Wo  (peak ws use: 48MB)
  u16* ob    = vbuf;         // attn out aliases v (dead after transpose)
  // after O-proj, q/k/v regions are dead:
  u16* W1b   = qb;           // 8MB
  u16* W2b   = kbuf;         // 8MB
  u16* mid   = vbuf;         // 8MB
  u16* h2    = h;
  float* x2  = out;          // attention residual lives in d_out (fp32)

  u16* Wqb = wqkvo;
  u16* Wkb = wqkvo + ((size_t)1 << 20);
  u16* Wvb = wqkvo + ((size_t)2 << 20);
  u16* Wob = wqkvo + ((size_t)3 << 20);

  // 0. QKV/O weights -> bf16
  wcvt4<<<dim3(2048), dim3(256), 0, stream>>>(Wq, Wk, Wv, Wo, wqkvo);
  // 1. LN1: x -> h (bf16)
  ln_kernel<<<dim3(BTOK), dim3(256), 0, stream>>>(x, g1, b1, h);
  // 2. fused QKV projections (q pre-scaled by SCALE*log2e)
  gemm3<0><<<dim3(24, BTOK / 128), 256, 0, stream>>>(
      h, GArg{Wqb, bq, qb, QSCL}, GArg{Wkb, bk, kbuf, 1.0f}, GArg{Wvb, bv, vbuf, 1.0f},
      nullptr, nullptr, DIM, DIM, 8);
  // 3. V transpose
  transpose_v<<<dim3(32, 32), 256, 0, stream>>>(vbuf, vtb);
  // 4. flash attention
  attn3<<<dim3(LSEQ / 128, 32), 256, 0, stream>>>(qb, kbuf, vtb, ob);
  // 5. O projection + residual -> x2 (= d_out, fp32)
  {
    GArg s{Wob, bo, nullptr, 1.0f};
    gemm3<1><<<dim3(8, BTOK / 128), 256, 0, stream>>>(ob, s, s, s, x, x2, DIM, DIM, 8);
  }
  // 5b. FFN weights -> bf16 (into dead q/k regions)
  wcvt2<<<dim3(4096), dim3(256), 0, stream>>>(W1, W2, W1b, W2b);
  // 6. LN2: x2 -> h2 (bf16)
  ln_kernel<<<dim3(BTOK), dim3(256), 0, stream>>>(x2, g2, b2, h2);
  // 7. FFN1 + GELU -> mid (bf16)
  {
    GArg s{W1b, bf1, mid, 1.0f};
    gemm3<2><<<dim3(32, BTOK / 128), 256, 0, stream>>>(h2, s, s, s, nullptr, nullptr, FFN, DIM, 32);
  }
  // 8. FFN2 + residual (in-place on d_out)
  {
    GArg s{W2b, bf2, nullptr, 1.0f};
    gemm3<1><<<dim3(8, BTOK / 128), 256, 0, stream>>>(mid, s, s, s, x2, out, DIM, FFN, 8);
  }
}

// Round 4
// 277.980 us; speedup vs baseline: 1.8787x; 1.1154x over previous
//
#include <hip/hip_runtime.h>
#include <hip/hip_bf16.h>
#include <math.h>

typedef unsigned short u16;
typedef __attribute__((ext_vector_type(8))) __bf16 bf16x8;
typedef __attribute__((ext_vector_type(4))) float f32x4;

#define DIM   1024
#define LSEQ  2048
#define BTOK  4096
#define HD    64
#define FFN   4096
// 1/sqrt(64) * log2(e), folded into Q at projection time so softmax is pure exp2
#define QSCL  0.18033688011112042f

__device__ __forceinline__ u16 f2bf(float f) {
  unsigned u = __builtin_bit_cast(unsigned, f);
  u += 0x7FFFu + ((u >> 16) & 1u);
  return (u16)(u >> 16);
}
__device__ __forceinline__ unsigned pk2(float a, float b) {
  return (unsigned)f2bf(a) | ((unsigned)f2bf(b) << 16);
}
__device__ __forceinline__ unsigned cvtpk(float lo, float hi) {
  unsigned r;
  asm("v_cvt_pk_bf16_f32 %0, %1, %2" : "=v"(r) : "v"(lo), "v"(hi));
  return r;
}
__device__ __forceinline__ f32x4 mfma16(bf16x8 a, bf16x8 b, f32x4 c) {
  return __builtin_amdgcn_mfma_f32_16x16x32_bf16(a, b, c, 0, 0, 0);
}
__device__ __forceinline__ void gload16(const void* g, void* l) {
  __builtin_amdgcn_global_load_lds((const __attribute__((address_space(1))) char*)g,
                                   (__attribute__((address_space(3))) char*)l, 16, 0, 0);
}
// gelu (tanh form): v * sigmoid(2*0.7978845608*(v + 0.044715 v^3)); exp via exp2
__device__ __forceinline__ float gelu_t(float v) {
  float v3 = v * v * v;
  float tt = fmaf(-0.10296766f, v3, -2.30258509f * v);  // -2*log2e*0.79788456*(v+0.044715v^3)
  return v * __builtin_amdgcn_rcpf(1.0f + exp2f(tt));
}

// ---------------- LayerNorm (fp32 in -> bf16 out) ----------------
__global__ __launch_bounds__(256) void ln_kernel(const float* __restrict__ x,
                                                 const float* __restrict__ g,
                                                 const float* __restrict__ bta,
                                                 u16* __restrict__ out) {
  int row = blockIdx.x, t = threadIdx.x;
  const float* xr = x + (size_t)row * DIM;
  float4 xv = *(const float4*)(xr + t * 4);
  float s  = xv.x + xv.y + xv.z + xv.w;
  float ss = xv.x * xv.x + xv.y * xv.y + xv.z * xv.z + xv.w * xv.w;
#pragma unroll
  for (int m = 32; m >= 1; m >>= 1) {
    s  += __shfl_xor(s, m);
    ss += __shfl_xor(ss, m);
  }
  __shared__ float red[8];
  if ((t & 63) == 0) { red[(t >> 6) * 2] = s; red[(t >> 6) * 2 + 1] = ss; }
  __syncthreads();
  s  = red[0] + red[2] + red[4] + red[6];
  ss = red[1] + red[3] + red[5] + red[7];
  float mu  = s * (1.0f / DIM);
  float var = ss * (1.0f / DIM) - mu * mu;
  float rs  = rsqrtf(var + 1e-5f);
  float4 gv = *(const float4*)(g + t * 4);
  float4 bv = *(const float4*)(bta + t * 4);
  uint2 o;
  o.x = pk2((xv.x - mu) * rs * gv.x + bv.x, (xv.y - mu) * rs * gv.y + bv.y);
  o.y = pk2((xv.z - mu) * rs * gv.z + bv.z, (xv.w - mu) * rs * gv.w + bv.w);
  *(uint2*)(out + (size_t)row * DIM + t * 4) = o;
}

// ---------------- weight fp32 -> bf16 ----------------
__global__ __launch_bounds__(256) void wcvt4(const float* __restrict__ Wq, const float* __restrict__ Wk,
                                             const float* __restrict__ Wv, const float* __restrict__ Wo,
                                             u16* __restrict__ dst) {
  int b = blockIdx.x;
  int r = b >> 9;
  const float* s = (r == 0) ? Wq : (r == 1) ? Wk : (r == 2) ? Wv : Wo;
  size_t i = (((size_t)(b & 511)) * 256 + threadIdx.x) * 8;
  float4 f0 = *(const float4*)(s + i), f1 = *(const float4*)(s + i + 4);
  uint4 o = { pk2(f0.x, f0.y), pk2(f0.z, f0.w), pk2(f1.x, f1.y), pk2(f1.z, f1.w) };
  *(uint4*)(dst + ((size_t)r << 20) + i) = o;
}
__global__ __launch_bounds__(256) void wcvt2(const float* __restrict__ W1, const float* __restrict__ W2,
                                             u16* __restrict__ d1, u16* __restrict__ d2) {
  int b = blockIdx.x;
  const float* s = (b < 2048) ? W1 : W2;
  u16* d = (b < 2048) ? d1 : d2;
  size_t i = (((size_t)(b & 2047)) * 256 + threadIdx.x) * 8;
  float4 f0 = *(const float4*)(s + i), f1 = *(const float4*)(s + i + 4);
  uint4 o = { pk2(f0.x, f0.y), pk2(f0.z, f0.w), pk2(f1.x, f1.y), pk2(f1.z, f1.w) };
  *(uint4*)(d + i) = o;
}

// ---------------- V transpose: v[b,l,h,c] -> vt[b,h,c,l] ----------------
__global__ __launch_bounds__(256) void transpose_v(const u16* __restrict__ v,
                                                   u16* __restrict__ vt) {
  __shared__ u16 tls[64][80];
  int jb = blockIdx.x, bh = blockIdx.y, b = bh >> 4, h = bh & 15;
  int t = threadIdx.x;
  int r = t >> 2, seg = t & 3;
  const u16* src = v + (size_t)(b * LSEQ + jb * 64 + r) * DIM + h * HD + seg * 16;
  *(uint4*)&tls[r][seg * 16]     = *(const uint4*)src;
  *(uint4*)&tls[r][seg * 16 + 8] = *(const uint4*)(src + 8);
  __syncthreads();
  int c = t >> 2, jseg = t & 3;
  u16 tmp[16] __attribute__((aligned(16)));
#pragma unroll
  for (int i = 0; i < 16; i++) tmp[i] = tls[jseg * 16 + i][c];
  u16* dst = vt + ((size_t)bh * HD + c) * LSEQ + jb * 64 + jseg * 16;
  *(uint4*)dst       = *(const uint4*)tmp;
  *(uint4*)(dst + 8) = *(const uint4*)(tmp + 8);
}

// ---------------- GEMM (2-phase dbuf): C[M,N] = A(bf16) @ W(bf16,[N,K])^T + bias ----------------
// EPI 0: outB = bf16((acc+bias)*oscale); 1: outF = acc+bias+resid (fp32); 2: outB = bf16(gelu(acc+bias))
struct GArg { const u16* Wb; const float* bias; u16* outB; float oscale; };

template <int EPI, int BM>
__global__ __launch_bounds__(256) void gemm3(const u16* __restrict__ A,
                                             GArg g0, GArg g1, GArg g2,
                                             const float* __restrict__ resid,
                                             float* __restrict__ outF,
                                             int N, int K, int nbPerW) {
  constexpr int WM = BM / 32;
  __shared__ u16 lsa[2][BM * 32];
  __shared__ u16 lsb[2][128 * 32];
  const int t = threadIdx.x;
  const int w = t >> 6, l = t & 63, l15 = l & 15, lg = l >> 4;
  const int wr = w >> 1, wc = w & 1;
  // bijective XCD-chunk remap (all launch grids have nwg % 8 == 0)
  const int nwg = gridDim.x * gridDim.y;
  int flat = blockIdx.y * gridDim.x + blockIdx.x;
  flat = (flat & 7) * (nwg >> 3) + (flat >> 3);
  const int bx = flat % gridDim.x, by = flat / gridDim.x;
  const int sel = bx / nbPerW, nb = bx % nbPerW;
  GArg G = (sel == 0) ? g0 : ((sel == 1) ? g1 : g2);
  const int n0 = nb * 128, m0 = by * BM;

  f32x4 acc[WM][4];
#pragma unroll
  for (int m = 0; m < WM; m++)
#pragma unroll
    for (int n = 0; n < 4; n++) acc[m][n] = (f32x4){0.f, 0.f, 0.f, 0.f};

  // staging: linear LDS dest, pre-swizzled global source (chunk ^= (row>>1)&3)
  const int grow = t >> 2;
  const int gcol = 8 * ((t & 3) ^ ((t >> 3) & 3));
  const u16* Asrc = A + (size_t)(m0 + grow) * K + gcol;
  const u16* Bsrc = G.Wb + (size_t)(n0 + grow) * K + gcol;
  const int rs = (l15 >> 1) & 3;  // read-side swizzle key

  auto stage = [&](int k0, int buf) {
#pragma unroll
    for (int i = 0; i < BM / 64; i++)
      gload16(Asrc + (size_t)i * 64 * K + k0, (char*)lsa + buf * (BM * 64) + i * 4096 + w * 1024);
#pragma unroll
    for (int i = 0; i < 2; i++)
      gload16(Bsrc + (size_t)i * 64 * K + k0, (char*)lsb + buf * 8192 + i * 4096 + w * 1024);
  };

  stage(0, 0);
  const int NT = K >> 5;
  for (int it = 0; it < NT; it++) {
    const int buf = it & 1;
    __syncthreads();                       // tile `it` ready (drains vmcnt+lgkm)
    if (it + 1 < NT) stage((it + 1) << 5, buf ^ 1);  // hides under this tile's compute

    bf16x8 af[WM], bfr[4];
#pragma unroll
    for (int m = 0; m < WM; m++)
      af[m] = *(const bf16x8*)&lsa[buf][(wr * (BM / 2) + m * 16 + l15) * 32 + (lg ^ rs) * 8];
#pragma unroll
    for (int n = 0; n < 4; n++)
      bfr[n] = *(const bf16x8*)&lsb[buf][(wc * 64 + n * 16 + l15) * 32 + (lg ^ rs) * 8];
#pragma unroll
    for (int m = 0; m < WM; m++)
#pragma unroll
      for (int n = 0; n < 4; n++)
        acc[m][n] = mfma16(af[m], bfr[n], acc[m][n]);
  }

#pragma unroll
  for (int m = 0; m < WM; m++) {
    const int row = m0 + wr * (BM / 2) + m * 16 + lg * 4;
#pragma unroll
    for (int n = 0; n < 4; n++) {
      const int col = n0 + wc * 64 + n * 16 + l15;
      const float bias = G.bias[col];
#pragma unroll
      for (int r = 0; r < 4; r++) {
        const float v = acc[m][n][r] + bias;
        const size_t idx = (size_t)(row + r) * N + col;
        if (EPI == 0)      G.outB[idx] = f2bf(v * G.oscale);
        else if (EPI == 1) outF[idx] = v + resid[idx];
        else               G.outB[idx] = f2bf(gelu_t(v));
      }
    }
  }
}

// ---------------- Flash attention v4 ----------------
// 64 q-rows/block (4 waves x 16 rows), 40KB LDS -> 4 blocks/CU, grid 1024.
// Zero per-tile cross-lane ops in steady state: lsum kept as per-lane partial,
// max shfl-chain only inside the (rare) rescale trigger.
__global__ __launch_bounds__(256) void attn4(const u16* __restrict__ q,
                                             const u16* __restrict__ k,
                                             const u16* __restrict__ vt,
                                             u16* __restrict__ o) {
  __shared__ u16 kls[2][64 * 64];  // [key][c], 16B chunks swizzled: c' = c ^ (row&7)
  __shared__ u16 vls[2][64 * 64];  // [c][key], same swizzle
  __shared__ u16 pls[4][16 * 64];  // per-wave P [q][key], swizzled
  const int t = threadIdx.x, w = t >> 6, l = t & 63, l15 = l & 15, lg = l >> 4;
  const int qbk = blockIdx.x, bh = blockIdx.y, b = bh >> 4, h = bh & 15;
  const int qrow0 = b * LSEQ + qbk * 64 + w * 16;

  bf16x8 av[2];
#pragma unroll
  for (int i = 0; i < 2; i++)
    av[i] = *(const bf16x8*)(q + (size_t)(qrow0 + l15) * DIM + h * HD + i * 32 + lg * 8);

  const int grow = t >> 3, gchk = t & 7;
  const u16* ksrc = k + (size_t)(b * LSEQ + grow) * DIM + h * HD + 8 * (gchk ^ (grow & 7));
  const u16* vsrc = vt + ((size_t)bh * HD + grow) * LSEQ + 8 * (gchk ^ (grow & 7));

  f32x4 oacc[4];
#pragma unroll
  for (int cb = 0; cb < 4; cb++) oacc[cb] = (f32x4){0.f, 0.f, 0.f, 0.f};
  float mrun = -INFINITY;
  float lsum = 0.f;  // per-lane partial (this lane's keys only); reduced in epilogue
  u16* pw = &pls[w][0];

  auto issueTile = [&](int jt, int buf) {
    const u16* kp = ksrc + (size_t)jt * DIM;
    const u16* vp = vsrc + jt;
#pragma unroll
    for (int i = 0; i < 2; i++) {
      gload16(kp + (size_t)i * 32 * DIM,  (char*)&kls[buf][0] + i * 4096 + w * 1024);
      gload16(vp + (size_t)i * 32 * LSEQ, (char*)&vls[buf][0] + i * 4096 + w * 1024);
    }
  };

  issueTile(0, 0);
  for (int it = 0; it < LSEQ / 64; it++) {
    const int buf = it & 1;
    __syncthreads();
    if (it + 1 < LSEQ / 64) issueTile((it + 1) * 64, buf ^ 1);

    // ---- QK^T (swapped: keys lane-local) ----
    f32x4 s[4];
#pragma unroll
    for (int cb = 0; cb < 4; cb++) s[cb] = (f32x4){0.f, 0.f, 0.f, 0.f};
    const u16* kb = &kls[buf][0];
    __builtin_amdgcn_s_setprio(1);
#pragma unroll
    for (int i = 0; i < 2; i++) {
#pragma unroll
      for (int cb = 0; cb < 4; cb++) {
        const int krow = cb * 16 + l15;
        bf16x8 kf = *(const bf16x8*)&kb[krow * 64 + (((i << 2) | lg) ^ (krow & 7)) * 8];
        s[cb] = mfma16(kf, av[i], s[cb]);
      }
    }
    __builtin_amdgcn_s_setprio(0);

    // ---- online softmax: lane owns q=l15, keys cb*16+lg*4+r ----
    float tm = fmaxf(fmaxf(fmaxf(s[0][0], s[0][1]), fmaxf(s[0][2], s[0][3])),
                     fmaxf(fmaxf(fmaxf(s[1][0], s[1][1]), fmaxf(s[1][2], s[1][3])),
                           fmaxf(fmaxf(fmaxf(s[2][0], s[2][1]), fmaxf(s[2][2], s[2][3])),
                                 fmaxf(fmaxf(s[3][0], s[3][1]), fmaxf(s[3][2], s[3][3])))));
    if (__any(tm > mrun + 8.0f)) {   // fires on tile 0, then ~never
      float tr = fmaxf(tm, __shfl_xor(tm, 16));
      tr = fmaxf(tr, __shfl_xor(tr, 32));
      const float mn = fmaxf(mrun, tr);
      const float scl = exp2f(mrun - mn);
      mrun = mn;
      lsum *= scl;
#pragma unroll
      for (int r = 0; r < 4; r++) {
        const float so = __shfl(scl, lg * 4 + r);
#pragma unroll
        for (int cb = 0; cb < 4; cb++) oacc[cb][r] *= so;
      }
    }
    float ps = 0.f;
    uint2 pk[4];
#pragma unroll
    for (int cb = 0; cb < 4; cb++) {
      float a0 = exp2f(s[cb][0] - mrun);
      float a1 = exp2f(s[cb][1] - mrun);
      float a2 = exp2f(s[cb][2] - mrun);
      float a3 = exp2f(s[cb][3] - mrun);
      ps += (a0 + a1) + (a2 + a3);
      pk[cb].x = cvtpk(a0, a1);
      pk[cb].y = cvtpk(a2, a3);
    }
    lsum += ps;
#pragma unroll
    for (int cb = 0; cb < 4; cb++) {
      const int c = 2 * cb + (lg >> 1);
      *(uint2*)((char*)pw + l15 * 128 + ((c ^ (l15 & 7)) * 16) + (lg & 1) * 8) = pk[cb];
    }

    // ---- PV ----
    const u16* vb = &vls[buf][0];
#pragma unroll
    for (int kt = 0; kt < 2; kt++) {
      bf16x8 pa = *(const bf16x8*)((char*)pw + l15 * 128 + (((4 * kt + lg) ^ (l15 & 7)) * 16));
      __builtin_amdgcn_s_setprio(1);
#pragma unroll
      for (int cb = 0; cb < 4; cb++) {
        const int vrow = cb * 16 + l15;
        bf16x8 vf = *(const bf16x8*)&vb[vrow * 64 + (((kt << 2) | lg) ^ (vrow & 7)) * 8];
        oacc[cb] = mfma16(pa, vf, oacc[cb]);
      }
      __builtin_amdgcn_s_setprio(0);
    }
  }

  // epilogue: reduce lsum across the 4 lane-groups, then normalize
  float rl = lsum + __shfl_xor(lsum, 16);
  rl += __shfl_xor(rl, 32);
#pragma unroll
  for (int r = 0; r < 4; r++) {
    const float lo = __shfl(rl, lg * 4 + r);
    const float rcp = 1.0f / lo;
#pragma unroll
    for (int cb = 0; cb < 4; cb++) {
      o[(size_t)(qrow0 + lg * 4 + r) * DIM + h * HD + cb * 16 + l15] =
          f2bf(oacc[cb][r] * rcp);
    }
  }
}

extern "C" void kernel_launch(void* const* d_in, const int* in_sizes, int n_in,
                              void* d_out, int out_size, void* d_ws, size_t ws_size,
                              hipStream_t stream) {
  const float* x   = (const float*)d_in[0];
  const float* g1  = (const float*)d_in[1];
  const float* b1  = (const float*)d_in[2];
  const float* Wq  = (const float*)d_in[3];
  const float* bq  = (const float*)d_in[4];
  const float* Wk  = (const float*)d_in[5];
  const float* bk  = (const float*)d_in[6];
  const float* Wv  = (const float*)d_in[7];
  const float* bv  = (const float*)d_in[8];
  const float* Wo  = (const float*)d_in[9];
  const float* bo  = (const float*)d_in[10];
  const float* g2  = (const float*)d_in[11];
  const float* b2  = (const float*)d_in[12];
  const float* W1  = (const float*)d_in[13];
  const float* bf1 = (const float*)d_in[14];
  const float* W2  = (const float*)d_in[15];
  const float* bf2 = (const float*)d_in[16];
  float* out = (float*)d_out;

  const size_t E = (size_t)BTOK * DIM;  // 4M elems
  u16* h     = (u16*)d_ws;   // 8MB
  u16* qb    = h + E;
  u16* kbuf  = qb + E;
  u16* vbuf  = kbuf + E;
  u16* vtb   = vbuf + E;
  u16* wqkvo = vtb + E;      // 8MB bf16 Wq|Wk|Wv|Wo  (peak ws use: 48MB)
  u16* ob    = vbuf;         // attn out aliases v (dead after transpose)
  // after O-proj, q/k/v regions are dead:
  u16* W1b   = qb;           // 8MB
  u16* W2b   = kbuf;         // 8MB
  u16* mid   = vbuf;         // 8MB
  u16* h2    = h;
  float* x2  = out;          // attention residual lives in d_out (fp32)

  u16* Wqb = wqkvo;
  u16* Wkb = wqkvo + ((size_t)1 << 20);
  u16* Wvb = wqkvo + ((size_t)2 << 20);
  u16* Wob = wqkvo + ((size_t)3 << 20);

  // 0. QKV/O weights -> bf16
  wcvt4<<<dim3(2048), dim3(256), 0, stream>>>(Wq, Wk, Wv, Wo, wqkvo);
  // 1. LN1: x -> h (bf16)
  ln_kernel<<<dim3(BTOK), dim3(256), 0, stream>>>(x, g1, b1, h);
  // 2. fused QKV projections (q pre-scaled by SCALE*log2e)
  gemm3<0, 128><<<dim3(24, BTOK / 128), 256, 0, stream>>>(
      h, GArg{Wqb, bq, qb, QSCL}, GArg{Wkb, bk, kbuf, 1.0f}, GArg{Wvb, bv, vbuf, 1.0f},
      nullptr, nullptr, DIM, DIM, 8);
  // 3. V transpose
  transpose_v<<<dim3(32, 32), 256, 0, stream>>>(vbuf, vtb);
  // 4. flash attention
  attn4<<<dim3(LSEQ / 64, 32), 256, 0, stream>>>(qb, kbuf, vtb, ob);
  // 5. O projection + residual -> x2 (= d_out, fp32)
  {
    GArg s{Wob, bo, nullptr, 1.0f};
    gemm3<1, 64><<<dim3(8, BTOK / 64), 256, 0, stream>>>(ob, s, s, s, x, x2, DIM, DIM, 8);
  }
  // 5b. FFN weights -> bf16 (into dead q/k regions)
  wcvt2<<<dim3(4096), dim3(256), 0, stream>>>(W1, W2, W1b, W2b);
  // 6. LN2: x2 -> h2 (bf16)
  ln_kernel<<<dim3(BTOK), dim3(256), 0, stream>>>(x2, g2, b2, h2);
  // 7. FFN1 + GELU -> mid (bf16)
  {
    GArg s{W1b, bf1, mid, 1.0f};
    gemm3<2, 128><<<dim3(32, BTOK / 128), 256, 0, stream>>>(h2, s, s, s, nullptr, nullptr, FFN, DIM, 32);
  }
  // 8. FFN2 + residual (in-place on d_out)
  {
    GArg s{W2b, bf2, nullptr, 1.0f};
    gemm3<1, 64><<<dim3(8, BTOK / 64), 256, 0, stream>>>(mid, s, s, s, x2, out, DIM, FFN, 8);
  }
}

// Round 5
// 254.990 us; speedup vs baseline: 2.0481x; 1.0902x over previous
//
#include <hip/hip_runtime.h>
#include <hip/hip_bf16.h>
#include <math.h>

typedef unsigned short u16;
typedef __attribute__((ext_vector_type(8))) __bf16 bf16x8;
typedef __attribute__((ext_vector_type(4))) float f32x4;

#define DIM   1024
#define LSEQ  2048
#define BTOK  4096
#define HD    64
#define FFN   4096
// 1/sqrt(64) * log2(e), folded into Q at projection time so softmax is pure exp2
#define QSCL  0.18033688011112042f

#if __has_builtin(__builtin_amdgcn_exp2f)
#define EXP2(x) __builtin_amdgcn_exp2f(x)
#else
#define EXP2(x) exp2f(x)
#endif

__device__ __forceinline__ u16 f2bf(float f) {
  unsigned u = __builtin_bit_cast(unsigned, f);
  u += 0x7FFFu + ((u >> 16) & 1u);
  return (u16)(u >> 16);
}
__device__ __forceinline__ unsigned pk2(float a, float b) {
  return (unsigned)f2bf(a) | ((unsigned)f2bf(b) << 16);
}
__device__ __forceinline__ unsigned cvtpk(float lo, float hi) {
  unsigned r;
  asm("v_cvt_pk_bf16_f32 %0, %1, %2" : "=v"(r) : "v"(lo), "v"(hi));
  return r;
}
__device__ __forceinline__ f32x4 mfma16(bf16x8 a, bf16x8 b, f32x4 c) {
  return __builtin_amdgcn_mfma_f32_16x16x32_bf16(a, b, c, 0, 0, 0);
}
__device__ __forceinline__ void gload16(const void* g, void* l) {
  __builtin_amdgcn_global_load_lds((const __attribute__((address_space(1))) char*)g,
                                   (__attribute__((address_space(3))) char*)l, 16, 0, 0);
}
// gelu (tanh form): v * sigmoid(2*0.7978845608*(v + 0.044715 v^3)); exp via exp2
__device__ __forceinline__ float gelu_t(float v) {
  float v3 = v * v * v;
  float tt = fmaf(-0.10296766f, v3, -2.30258509f * v);
  return v * __builtin_amdgcn_rcpf(1.0f + EXP2(tt));
}

// ---------------- LayerNorm (fp32 in -> bf16 out) ----------------
__global__ __launch_bounds__(256) void ln_kernel(const float* __restrict__ x,
                                                 const float* __restrict__ g,
                                                 const float* __restrict__ bta,
                                                 u16* __restrict__ out) {
  int row = blockIdx.x, t = threadIdx.x;
  const float* xr = x + (size_t)row * DIM;
  float4 xv = *(const float4*)(xr + t * 4);
  float s  = xv.x + xv.y + xv.z + xv.w;
  float ss = xv.x * xv.x + xv.y * xv.y + xv.z * xv.z + xv.w * xv.w;
#pragma unroll
  for (int m = 32; m >= 1; m >>= 1) {
    s  += __shfl_xor(s, m);
    ss += __shfl_xor(ss, m);
  }
  __shared__ float red[8];
  if ((t & 63) == 0) { red[(t >> 6) * 2] = s; red[(t >> 6) * 2 + 1] = ss; }
  __syncthreads();
  s  = red[0] + red[2] + red[4] + red[6];
  ss = red[1] + red[3] + red[5] + red[7];
  float mu  = s * (1.0f / DIM);
  float var = ss * (1.0f / DIM) - mu * mu;
  float rs  = rsqrtf(var + 1e-5f);
  float4 gv = *(const float4*)(g + t * 4);
  float4 bv = *(const float4*)(bta + t * 4);
  uint2 o;
  o.x = pk2((xv.x - mu) * rs * gv.x + bv.x, (xv.y - mu) * rs * gv.y + bv.y);
  o.y = pk2((xv.z - mu) * rs * gv.z + bv.z, (xv.w - mu) * rs * gv.w + bv.w);
  *(uint2*)(out + (size_t)row * DIM + t * 4) = o;
}

// ---------------- weight fp32 -> bf16 ----------------
__global__ __launch_bounds__(256) void wcvt4(const float* __restrict__ Wq, const float* __restrict__ Wk,
                                             const float* __restrict__ Wv, const float* __restrict__ Wo,
                                             u16* __restrict__ dst) {
  int b = blockIdx.x;
  int r = b >> 9;
  const float* s = (r == 0) ? Wq : (r == 1) ? Wk : (r == 2) ? Wv : Wo;
  size_t i = (((size_t)(b & 511)) * 256 + threadIdx.x) * 8;
  float4 f0 = *(const float4*)(s + i), f1 = *(const float4*)(s + i + 4);
  uint4 o = { pk2(f0.x, f0.y), pk2(f0.z, f0.w), pk2(f1.x, f1.y), pk2(f1.z, f1.w) };
  *(uint4*)(dst + ((size_t)r << 20) + i) = o;
}
__global__ __launch_bounds__(256) void wcvt2(const float* __restrict__ W1, const float* __restrict__ W2,
                                             u16* __restrict__ d1, u16* __restrict__ d2) {
  int b = blockIdx.x;
  const float* s = (b < 2048) ? W1 : W2;
  u16* d = (b < 2048) ? d1 : d2;
  size_t i = (((size_t)(b & 2047)) * 256 + threadIdx.x) * 8;
  float4 f0 = *(const float4*)(s + i), f1 = *(const float4*)(s + i + 4);
  uint4 o = { pk2(f0.x, f0.y), pk2(f0.z, f0.w), pk2(f1.x, f1.y), pk2(f1.z, f1.w) };
  *(uint4*)(d + i) = o;
}

// ---------------- V transpose: v[b,l,h,c] -> vt[b,h,c,l] ----------------
__global__ __launch_bounds__(256) void transpose_v(const u16* __restrict__ v,
                                                   u16* __restrict__ vt) {
  __shared__ u16 tls[64][80];
  int jb = blockIdx.x, bh = blockIdx.y, b = bh >> 4, h = bh & 15;
  int t = threadIdx.x;
  int r = t >> 2, seg = t & 3;
  const u16* src = v + (size_t)(b * LSEQ + jb * 64 + r) * DIM + h * HD + seg * 16;
  *(uint4*)&tls[r][seg * 16]     = *(const uint4*)src;
  *(uint4*)&tls[r][seg * 16 + 8] = *(const uint4*)(src + 8);
  __syncthreads();
  int c = t >> 2, jseg = t & 3;
  u16 tmp[16] __attribute__((aligned(16)));
#pragma unroll
  for (int i = 0; i < 16; i++) tmp[i] = tls[jseg * 16 + i][c];
  u16* dst = vt + ((size_t)bh * HD + c) * LSEQ + jb * 64 + jseg * 16;
  *(uint4*)dst       = *(const uint4*)tmp;
  *(uint4*)(dst + 8) = *(const uint4*)(tmp + 8);
}

// ---------------- GEMM (2-phase dbuf): C[M,N] = A(bf16) @ W(bf16,[N,K])^T + bias ----------------
// EPI 0: outB = bf16((acc+bias)*oscale); 1: outF = acc+bias+resid (fp32); 2: outB = bf16(gelu(acc+bias))
struct GArg { const u16* Wb; const float* bias; u16* outB; float oscale; };

template <int EPI, int BM>
__global__ __launch_bounds__(256) void gemm3(const u16* __restrict__ A,
                                             GArg g0, GArg g1, GArg g2,
                                             const float* __restrict__ resid,
                                             float* __restrict__ outF,
                                             int N, int K, int nbPerW) {
  constexpr int WM = BM / 32;
  constexpr int ABUF = BM * 64;  // bytes per A double-buffer half
  __shared__ u16 lsa[2][BM * 32];
  __shared__ u16 lsb[2][128 * 32];
  const int t = threadIdx.x;
  const int w = t >> 6, l = t & 63, l15 = l & 15, lg = l >> 4;
  const int wr = w >> 1, wc = w & 1;
  // bijective XCD-chunk remap (all launch grids have nwg % 8 == 0)
  const int nwg = gridDim.x * gridDim.y;
  int flat = blockIdx.y * gridDim.x + blockIdx.x;
  flat = (flat & 7) * (nwg >> 3) + (flat >> 3);
  const int bx = flat % gridDim.x, by = flat / gridDim.x;
  const int sel = bx / nbPerW, nb = bx % nbPerW;
  GArg G = (sel == 0) ? g0 : ((sel == 1) ? g1 : g2);
  const int n0 = nb * 128, m0 = by * BM;

  f32x4 acc[WM][4];
#pragma unroll
  for (int m = 0; m < WM; m++)
#pragma unroll
    for (int n = 0; n < 4; n++) acc[m][n] = (f32x4){0.f, 0.f, 0.f, 0.f};

  // staging: linear LDS dest, pre-swizzled global source (chunk ^= (row>>1)&3)
  const int grow = t >> 2;
  const int gcol = 8 * ((t & 3) ^ ((t >> 3) & 3));
  const u16* Asrc = A + (size_t)(m0 + grow) * K + gcol;
  const u16* Bsrc = G.Wb + (size_t)(n0 + grow) * K + gcol;
  const int rs = (l15 >> 1) & 3;  // read-side swizzle key

  // hoisted LDS read bases; per-tile cost = 2 adds, fragment index via imm offset
  const char* aadr = (const char*)lsa + (wr * (BM / 2) + l15) * 64 + (lg ^ rs) * 16;
  const char* badr = (const char*)lsb + (wc * 64 + l15) * 64 + (lg ^ rs) * 16;

  auto stage = [&](int k0, int buf) {
#pragma unroll
    for (int i = 0; i < BM / 64; i++)
      gload16(Asrc + (size_t)i * 64 * K + k0, (char*)lsa + buf * ABUF + i * 4096 + w * 1024);
#pragma unroll
    for (int i = 0; i < 2; i++)
      gload16(Bsrc + (size_t)i * 64 * K + k0, (char*)lsb + buf * 8192 + i * 4096 + w * 1024);
  };

  stage(0, 0);
  const int NT = K >> 5;
  for (int it = 0; it < NT; it++) {
    const int buf = it & 1;
    __syncthreads();                       // tile `it` ready (drains vmcnt+lgkm)
    if (it + 1 < NT) stage((it + 1) << 5, buf ^ 1);  // hides under this tile's compute

    const char* ap = aadr + buf * ABUF;
    const char* bp = badr + buf * 8192;
    bf16x8 af[WM], bfr[4];
#pragma unroll
    for (int m = 0; m < WM; m++)
      af[m] = *(const bf16x8*)(ap + m * 1024);
#pragma unroll
    for (int n = 0; n < 4; n++)
      bfr[n] = *(const bf16x8*)(bp + n * 1024);
#pragma unroll
    for (int m = 0; m < WM; m++)
#pragma unroll
      for (int n = 0; n < 4; n++)
        acc[m][n] = mfma16(af[m], bfr[n], acc[m][n]);
  }

#pragma unroll
  for (int m = 0; m < WM; m++) {
    const int row = m0 + wr * (BM / 2) + m * 16 + lg * 4;
#pragma unroll
    for (int n = 0; n < 4; n++) {
      const int col = n0 + wc * 64 + n * 16 + l15;
      const float bias = G.bias[col];
#pragma unroll
      for (int r = 0; r < 4; r++) {
        const float v = acc[m][n][r] + bias;
        const size_t idx = (size_t)(row + r) * N + col;
        if (EPI == 0)      G.outB[idx] = f2bf(v * G.oscale);
        else if (EPI == 1) outF[idx] = v + resid[idx];
        else               G.outB[idx] = f2bf(gelu_t(v));
      }
    }
  }
}

// ---------------- Flash attention v5 ----------------
// 64 q-rows/block, 40KB LDS, 4 blocks/CU. All LDS addresses hoisted (imm offsets),
// S-accumulator initialized with -mrun via MFMA C-operand, hw exp2, XCD-chunked blocks.
__global__ __launch_bounds__(256, 4) void attn5(const u16* __restrict__ q,
                                                const u16* __restrict__ k,
                                                const u16* __restrict__ vt,
                                                u16* __restrict__ o) {
  // layout: K[2][8192] @0 | V[2][8192] @16384 | P[4][2048] @32768
  __shared__ __align__(16) char smem[40960];
  const int t = threadIdx.x, w = t >> 6, l = t & 63, l15 = l & 15, lg = l >> 4;
  int flat = blockIdx.y * gridDim.x + blockIdx.x;   // 1024 blocks
  flat = (flat & 7) * 128 + (flat >> 3);            // XCD-chunked: 4 heads per XCD
  const int qbk = flat & 31, bh = flat >> 5;
  const int b = bh >> 4, h = bh & 15;
  const int qrow0 = b * LSEQ + qbk * 64 + w * 16;
  const int r7 = l15 & 7;
  const int c0 = lg ^ r7;  // 3-bit physical chunk for slot 0 (slot 1 = c0^4)

  bf16x8 av[2];
#pragma unroll
  for (int i = 0; i < 2; i++)
    av[i] = *(const bf16x8*)(q + (size_t)(qrow0 + l15) * DIM + h * HD + i * 32 + lg * 8);

  // hoisted LDS read/write addresses (loop-invariant; per-tile = +buf*8192)
  const char* adrA  = smem + l15 * 128 + c0 * 16;            // K/V slot 0 -> pairs av[0]
  const char* adrB  = smem + l15 * 128 + (c0 ^ 4) * 16;      // K/V slot 1 -> pairs av[1]
  const char* padrA = smem + 32768 + w * 2048 + l15 * 128 + c0 * 16;
  const char* padrB = smem + 32768 + w * 2048 + l15 * 128 + (c0 ^ 4) * 16;
  char* pwa[4];
#pragma unroll
  for (int cb = 0; cb < 4; cb++)
    pwa[cb] = smem + 32768 + w * 2048 + l15 * 128 +
              (((2 * cb + (lg >> 1)) ^ r7) * 16) + (lg & 1) * 8;

  const int grow = t >> 3, gchk = t & 7;
  const u16* ksrc = k + (size_t)(b * LSEQ + grow) * DIM + h * HD + 8 * (gchk ^ (grow & 7));
  const u16* vsrc = vt + ((size_t)bh * HD + grow) * LSEQ + 8 * (gchk ^ (grow & 7));

  f32x4 oacc[4];
#pragma unroll
  for (int cb = 0; cb < 4; cb++) oacc[cb] = (f32x4){0.f, 0.f, 0.f, 0.f};
  f32x4 minit = (f32x4){0.f, 0.f, 0.f, 0.f};  // holds -mrun (splat); state of the running max
  float lsum = 0.f;                           // per-lane partial; reduced in epilogue

  auto issueTile = [&](int jt, int buf) {
    const u16* kp = ksrc + (size_t)jt * DIM;
    const u16* vp = vsrc + jt;
#pragma unroll
    for (int i = 0; i < 2; i++) {
      gload16(kp + (size_t)i * 32 * DIM,  smem + buf * 8192 + i * 4096 + w * 1024);
      gload16(vp + (size_t)i * 32 * LSEQ, smem + 16384 + buf * 8192 + i * 4096 + w * 1024);
    }
  };

  issueTile(0, 0);
  for (int it = 0; it < LSEQ / 64; it++) {
    const int buf = it & 1;
    __syncthreads();
    if (it + 1 < LSEQ / 64) issueTile((it + 1) * 64, buf ^ 1);
    const int ko = buf * 8192;

    // ---- QK^T (swapped: keys lane-local); C-init = -mrun ----
    f32x4 s[4];
    const char* kA = adrA + ko;
    const char* kB = adrB + ko;
    __builtin_amdgcn_s_setprio(1);
#pragma unroll
    for (int cb = 0; cb < 4; cb++) {
      bf16x8 kf0 = *(const bf16x8*)(kA + cb * 2048);
      bf16x8 kf1 = *(const bf16x8*)(kB + cb * 2048);
      s[cb] = mfma16(kf0, av[0], minit);
      s[cb] = mfma16(kf1, av[1], s[cb]);
    }
    __builtin_amdgcn_s_setprio(0);

    // ---- online softmax: s already = S - mrun ----
    float tm = fmaxf(fmaxf(fmaxf(s[0][0], s[0][1]), fmaxf(s[0][2], s[0][3])),
                     fmaxf(fmaxf(fmaxf(s[1][0], s[1][1]), fmaxf(s[1][2], s[1][3])),
                           fmaxf(fmaxf(fmaxf(s[2][0], s[2][1]), fmaxf(s[2][2], s[2][3])),
                                 fmaxf(fmaxf(s[3][0], s[3][1]), fmaxf(s[3][2], s[3][3])))));
    if (__any(tm > 8.0f)) {  // rare: renormalize running max
      float tr = fmaxf(tm, __shfl_xor(tm, 16));
      tr = fmaxf(tr, __shfl_xor(tr, 32));
      const float d = fmaxf(tr, 0.f);
      const float scl = EXP2(-d);
      const f32x4 dv = (f32x4){d, d, d, d};
      lsum *= scl;
      minit -= dv;
#pragma unroll
      for (int cb = 0; cb < 4; cb++) s[cb] -= dv;
#pragma unroll
      for (int r = 0; r < 4; r++) {
        const float so = __shfl(scl, lg * 4 + r);
#pragma unroll
        for (int cb = 0; cb < 4; cb++) oacc[cb][r] *= so;
      }
    }
    float ps = 0.f;
    uint2 pk[4];
#pragma unroll
    for (int cb = 0; cb < 4; cb++) {
      float a0 = EXP2(s[cb][0]);
      float a1 = EXP2(s[cb][1]);
      float a2 = EXP2(s[cb][2]);
      float a3 = EXP2(s[cb][3]);
      ps += (a0 + a1) + (a2 + a3);
      pk[cb].x = cvtpk(a0, a1);
      pk[cb].y = cvtpk(a2, a3);
    }
    lsum += ps;
#pragma unroll
    for (int cb = 0; cb < 4; cb++) *(uint2*)pwa[cb] = pk[cb];

    // ---- PV ----
    const char* vA = adrA + ko + 16384;
    const char* vB = adrB + ko + 16384;
    bf16x8 pa0 = *(const bf16x8*)padrA;
    bf16x8 pa1 = *(const bf16x8*)padrB;
    __builtin_amdgcn_s_setprio(1);
#pragma unroll
    for (int cb = 0; cb < 4; cb++) {
      bf16x8 vf0 = *(const bf16x8*)(vA + cb * 2048);
      oacc[cb] = mfma16(pa0, vf0, oacc[cb]);
    }
#pragma unroll
    for (int cb = 0; cb < 4; cb++) {
      bf16x8 vf1 = *(const bf16x8*)(vB + cb * 2048);
      oacc[cb] = mfma16(pa1, vf1, oacc[cb]);
    }
    __builtin_amdgcn_s_setprio(0);
  }

  // epilogue: reduce lsum across the 4 lane-groups, then normalize
  float rl = lsum + __shfl_xor(lsum, 16);
  rl += __shfl_xor(rl, 32);
#pragma unroll
  for (int r = 0; r < 4; r++) {
    const float lo = __shfl(rl, lg * 4 + r);
    const float rcp = 1.0f / lo;
#pragma unroll
    for (int cb = 0; cb < 4; cb++) {
      o[(size_t)(qrow0 + lg * 4 + r) * DIM + h * HD + cb * 16 + l15] =
          f2bf(oacc[cb][r] * rcp);
    }
  }
}

extern "C" void kernel_launch(void* const* d_in, const int* in_sizes, int n_in,
                              void* d_out, int out_size, void* d_ws, size_t ws_size,
                              hipStream_t stream) {
  const float* x   = (const float*)d_in[0];
  const float* g1  = (const float*)d_in[1];
  const float* b1  = (const float*)d_in[2];
  const float* Wq  = (const float*)d_in[3];
  const float* bq  = (const float*)d_in[4];
  const float* Wk  = (const float*)d_in[5];
  const float* bk  = (const float*)d_in[6];
  const float* Wv  = (const float*)d_in[7];
  const float* bv  = (const float*)d_in[8];
  const float* Wo  = (const float*)d_in[9];
  const float* bo  = (const float*)d_in[10];
  const float* g2  = (const float*)d_in[11];
  const float* b2  = (const float*)d_in[12];
  const float* W1  = (const float*)d_in[13];
  const float* bf1 = (const float*)d_in[14];
  const float* W2  = (const float*)d_in[15];
  const float* bf2 = (const float*)d_in[16];
  float* out = (float*)d_out;

  const size_t E = (size_t)BTOK * DIM;  // 4M elems
  u16* h     = (u16*)d_ws;   // 8MB
  u16* qb    = h + E;
  u16* kbuf  = qb + E;
  u16* vbuf  = kbuf + E;
  u16* vtb   = vbuf + E;
  u16* wqkvo = vtb + E;      // 8MB bf16 Wq|Wk|Wv|Wo  (peak ws use: 48MB)
  u16* ob    = vbuf;         // attn out aliases v (dead after transpose)
  // after O-proj, q/k/v regions are dead:
  u16* W1b   = qb;           // 8MB
  u16* W2b   = kbuf;         // 8MB
  u16* mid   = vbuf;         // 8MB
  u16* h2    = h;
  float* x2  = out;          // attention residual lives in d_out (fp32)

  u16* Wqb = wqkvo;
  u16* Wkb = wqkvo + ((size_t)1 << 20);
  u16* Wvb = wqkvo + ((size_t)2 << 20);
  u16* Wob = wqkvo + ((size_t)3 << 20);

  // 0. QKV/O weights -> bf16
  wcvt4<<<dim3(2048), dim3(256), 0, stream>>>(Wq, Wk, Wv, Wo, wqkvo);
  // 1. LN1: x -> h (bf16)
  ln_kernel<<<dim3(BTOK), dim3(256), 0, stream>>>(x, g1, b1, h);
  // 2. fused QKV projections (q pre-scaled by SCALE*log2e)
  gemm3<0, 128><<<dim3(24, BTOK / 128), 256, 0, stream>>>(
      h, GArg{Wqb, bq, qb, QSCL}, GArg{Wkb, bk, kbuf, 1.0f}, GArg{Wvb, bv, vbuf, 1.0f},
      nullptr, nullptr, DIM, DIM, 8);
  // 3. V transpose
  transpose_v<<<dim3(32, 32), 256, 0, stream>>>(vbuf, vtb);
  // 4. flash attention
  attn5<<<dim3(LSEQ / 64, 32), 256, 0, stream>>>(qb, kbuf, vtb, ob);
  // 5. O projection + residual -> x2 (= d_out, fp32)
  {
    GArg s{Wob, bo, nullptr, 1.0f};
    gemm3<1, 64><<<dim3(8, BTOK / 64), 256, 0, stream>>>(ob, s, s, s, x, x2, DIM, DIM, 8);
  }
  // 5b. FFN weights -> bf16 (into dead q/k regions)
  wcvt2<<<dim3(4096), dim3(256), 0, stream>>>(W1, W2, W1b, W2b);
  // 6. LN2: x2 -> h2 (bf16)
  ln_kernel<<<dim3(BTOK), dim3(256), 0, stream>>>(x2, g2, b2, h2);
  // 7. FFN1 + GELU -> mid (bf16)
  {
    GArg s{W1b, bf1, mid, 1.0f};
    gemm3<2, 128><<<dim3(32, BTOK / 128), 256, 0, stream>>>(h2, s, s, s, nullptr, nullptr, FFN, DIM, 32);
  }
  // 8. FFN2 + residual (in-place on d_out)
  {
    GArg s{W2b, bf2, nullptr, 1.0f};
    gemm3<1, 64><<<dim3(8, BTOK / 64), 256, 0, stream>>>(mid, s, s, s, x2, out, DIM, FFN, 8);
  }
}